// Round 13
// baseline (322.076 us; speedup 1.0000x reference)
//
#include <hip/hip_runtime.h>

typedef unsigned short u16;
typedef short bf16x8 __attribute__((ext_vector_type(8)));
typedef float f32x4 __attribute__((ext_vector_type(4)));

#define B_ 2
#define S_ 2048
#define D_ 2048
#define HD_ 128
#define GW 512   // head-group width for fallback path
#define KB 64    // attention KV tile rows
#define VST 72   // Vt row stride (u16)
#define PST 72   // Ps row stride (u16)

__device__ __forceinline__ float bf2f(u16 h) {
  unsigned u = ((unsigned)h) << 16;
  return __builtin_bit_cast(float, u);
}
__device__ __forceinline__ u16 f2bf(float f) {
  unsigned u = __builtin_bit_cast(unsigned, f);
  u += 0x7FFF + ((u >> 16) & 1);
  return (u16)(u >> 16);
}
__device__ __forceinline__ bf16x8 cvt8(const float* p) {
  float4 a = *(const float4*)p;
  float4 b = *(const float4*)(p + 4);
  bf16x8 r;
  r[0] = (short)f2bf(a.x); r[1] = (short)f2bf(a.y);
  r[2] = (short)f2bf(a.z); r[3] = (short)f2bf(a.w);
  r[4] = (short)f2bf(b.x); r[5] = (short)f2bf(b.y);
  r[6] = (short)f2bf(b.z); r[7] = (short)f2bf(b.w);
  return r;
}

__device__ __forceinline__ void gload16(const void* g, void* lds) {
  __builtin_amdgcn_global_load_lds(
      (const __attribute__((address_space(1))) unsigned*)g,
      (__attribute__((address_space(3))) unsigned*)lds, 16, 0, 0);
}

__device__ __forceinline__ f32x4 mfma16(bf16x8 a, bf16x8 b, f32x4 c) {
  return __builtin_amdgcn_mfma_f32_16x16x32_bf16(a, b, c, 0, 0, 0);
}

// ---------------- f32 -> bf16 bulk convert + RoPE table. Grid (4096, ny).
__global__ void k_cvt_all(const float* __restrict__ x, const float* __restrict__ wq,
                          const float* __restrict__ wk, const float* __restrict__ wv,
                          const float* __restrict__ wo, u16* __restrict__ xb,
                          u16* __restrict__ wqkvb, u16* wob, float2* tab) {
  const int slice = blockIdx.y;
  const int i = blockIdx.x * 256 + threadIdx.x;
  if (slice == 5) {
    if (tab != nullptr && i < 131072) {  // 2048 x 64
      const int s = i >> 6, ip = i & 63;
      const float freq = expf(-(float)ip * 0.14391157f);  // ln(10000)/64
      float sv, cv;
      sincosf((float)s * freq, &sv, &cv);
      tab[i] = make_float2(cv, sv);
    }
    return;
  }
  if (slice == 4 && wob == nullptr) return;
  const float* src;
  u16* dst;
  int n8;
  if (slice == 0) { src = x; dst = xb; n8 = 1048576; }
  else if (slice == 1) { src = wq; dst = wqkvb; n8 = 524288; }
  else if (slice == 2) { src = wk; dst = wqkvb + 4194304; n8 = 524288; }
  else if (slice == 3) { src = wv; dst = wqkvb + 8388608; n8 = 524288; }
  else { src = wo; dst = wob; n8 = 524288; }
  if (i < n8) *(bf16x8*)(dst + (size_t)i * 8) = cvt8(src + (size_t)i * 8);
}

// ---------------- 128x256 / BK=64 / 8-wave QKV GEMM, 768 blocks = 3 exact
// dispatch rounds (fixes R11/R12's 75% tail). 2 phases/K-tile, each
// {8 ds_read + prefetch-issue -> bar -> lgkm(0) -> 16 MFMA -> bar}.
// Swizzle chunk^=(row&7) (verified, 0 conflicts). vmcnt(0) once per K-tile
// drains only own prefetch. B-panel reuse stride = gridDim.x = 8 = NXCD ->
// weights stay XCD-L2-local.
__global__ __launch_bounds__(512) void k_gemm_qkv_128x256(
    const u16* __restrict__ xb, const u16* __restrict__ wqkvb,
    const float* __restrict__ bq, const float* __restrict__ bk,
    const float* __restrict__ bv, u16* __restrict__ q, u16* __restrict__ k,
    u16* __restrict__ v, const float2* __restrict__ tab) {
  constexpr int K = 2048, NT = 32;
  __shared__ u16 SA[2][128 * 64];
  __shared__ u16 SB[2][256 * 64];
  const int z = blockIdx.z;
  const u16* W = wqkvb + (size_t)z * D_ * D_;
  const float* bias = z == 0 ? bq : (z == 1 ? bk : bv);
  u16* C = z == 0 ? q : (z == 1 ? k : v);
  const float2* tb = z == 2 ? nullptr : tab;

  const int t = threadIdx.x, wid = t >> 6, l = t & 63, lr = l & 15, lg = l >> 4;
  const int wm = wid >> 2, wn = wid & 3;  // wave tile: 64 rows x 64 cols
  const int m0 = blockIdx.y * 128, n0 = blockIdx.x * 256;

  const int srow = wid * 8 + (l >> 3);  // staging row (mod 64)
  const int sc = (l & 7) ^ (srow & 7);  // pre-swizzled source chunk

  f32x4 acc[4][4];
#pragma unroll
  for (int i = 0; i < 4; ++i)
#pragma unroll
    for (int j = 0; j < 4; ++j) acc[i][j] = f32x4{0.f, 0.f, 0.f, 0.f};

  // prologue: stage tile 0 into slot 0 (A: 2 rounds, B: 4 rounds), drain, bar
#pragma unroll
  for (int r = 0; r < 2; ++r)
    gload16(xb + (size_t)(m0 + r * 64 + srow) * K + sc * 8,
            (void*)(SA[0] + (size_t)(r * 64 + wid * 8) * 64));
#pragma unroll
  for (int r = 0; r < 4; ++r)
    gload16(W + (size_t)(n0 + r * 64 + srow) * K + sc * 8,
            (void*)(SB[0] + (size_t)(r * 64 + wid * 8) * 64));
  asm volatile("s_waitcnt vmcnt(0)" ::: "memory");
  __builtin_amdgcn_sched_barrier(0);
  __builtin_amdgcn_s_barrier();
  __builtin_amdgcn_sched_barrier(0);

#define LOADQ(ks)                                                              \
  {                                                                            \
    const int ch8 = (((ks)*4 + lg) ^ (lr & 7)) * 8;                            \
    _Pragma("unroll") for (int i = 0; i < 4; ++i) af[i] =                      \
        *(const bf16x8*)(sa + (size_t)(wm * 64 + i * 16 + lr) * 64 + ch8);     \
    _Pragma("unroll") for (int j = 0; j < 4; ++j) bf[j] =                      \
        *(const bf16x8*)(sb + (size_t)(wn * 64 + j * 16 + lr) * 64 + ch8);     \
  }
#define MFMAQ()                                                                \
  asm volatile("s_waitcnt lgkmcnt(0)" ::: "memory");                           \
  __builtin_amdgcn_sched_barrier(0);                                           \
  __builtin_amdgcn_s_setprio(1);                                               \
  _Pragma("unroll") for (int i = 0; i < 4; ++i)                                \
      _Pragma("unroll") for (int j = 0; j < 4; ++j)                            \
          acc[i][j] = mfma16(af[i], bf[j], acc[i][j]);                         \
  __builtin_amdgcn_s_setprio(0);                                               \
  __builtin_amdgcn_sched_barrier(0);

  for (int tt = 0; tt < NT; ++tt) {
    const int slot = tt & 1;
    const u16* sa = SA[slot];
    const u16* sb = SB[slot];
    u16* da = SA[slot ^ 1];
    u16* db = SB[slot ^ 1];
    const bool more = (tt + 1 < NT);
    const int kt = (tt + 1) * 64;
    bf16x8 af[4], bf[4];

    // phase 0: ks=0; stage A(tt+1) + B(tt+1) rounds 0,1
    LOADQ(0);
    if (more) {
#pragma unroll
      for (int r = 0; r < 2; ++r)
        gload16(xb + (size_t)(m0 + r * 64 + srow) * K + kt + sc * 8,
                (void*)(da + (size_t)(r * 64 + wid * 8) * 64));
#pragma unroll
      for (int r = 0; r < 2; ++r)
        gload16(W + (size_t)(n0 + r * 64 + srow) * K + kt + sc * 8,
                (void*)(db + (size_t)(r * 64 + wid * 8) * 64));
    }
    __builtin_amdgcn_s_barrier();
    MFMAQ();
    __builtin_amdgcn_s_barrier();

    // phase 1: ks=1; stage B(tt+1) rounds 2,3; drain own prefetch
    LOADQ(1);
    if (more) {
#pragma unroll
      for (int r = 2; r < 4; ++r)
        gload16(W + (size_t)(n0 + r * 64 + srow) * K + kt + sc * 8,
                (void*)(db + (size_t)(r * 64 + wid * 8) * 64));
    }
    asm volatile("s_waitcnt vmcnt(0)" ::: "memory");
    __builtin_amdgcn_sched_barrier(0);
    __builtin_amdgcn_s_barrier();
    MFMAQ();
    __builtin_amdgcn_s_barrier();
  }
#undef LOADQ
#undef MFMAQ

  // epilogue: bias + optional fused interleaved RoPE
#pragma unroll
  for (int i = 0; i < 4; ++i) {
#pragma unroll
    for (int j = 0; j < 4; ++j) {
      const int col = n0 + wn * 64 + j * 16 + lr;
      const float bv_ = bias[col];
      const int row = m0 + wm * 64 + i * 16 + lg * 4;
      if (tb != nullptr) {
        const int ip = (col & 127) >> 1;
        const int odd = col & 1;
#pragma unroll
        for (int r = 0; r < 4; ++r) {
          const float vv = acc[i][j][r] + bv_;
          const float pp = __shfl_xor(vv, 1, 64);
          const float2 cs = tb[((row + r) & (S_ - 1)) * 64 + ip];
          const float o = odd ? (pp * cs.y + vv * cs.x) : (vv * cs.x - pp * cs.y);
          C[(size_t)(row + r) * D_ + col] = f2bf(o);
        }
      } else {
#pragma unroll
        for (int r = 0; r < 4; ++r)
          C[(size_t)(row + r) * D_ + col] = f2bf(acc[i][j][r] + bv_);
      }
    }
  }
}

// ---------------- m97-structure GEMM (kept for out-proj and fallbacks)
template <int AM, int WM, int CM>
__device__ __forceinline__ void gemm_body(const void* Ap, const void* Wp,
                                          const float* __restrict__ bias,
                                          void* Cp, int ldc) {
  constexpr int K = 2048;
  __shared__ u16 As[128 * 32];
  __shared__ u16 Bs[128 * 32];
  const int t = threadIdx.x;
  const int w = t >> 6, l = t & 63, lr = l & 15, lg = l >> 4;
  const int m0 = blockIdx.y * 128, n0 = blockIdx.x * 128;
  const int wr = w >> 1, wc = w & 1;

  f32x4 acc[4][4];
#pragma unroll
  for (int i = 0; i < 4; ++i)
#pragma unroll
    for (int j = 0; j < 4; ++j) acc[i][j] = f32x4{0.f, 0.f, 0.f, 0.f};

  const int rowA0 = t >> 2, ko0 = (t & 3) * 8;
  const int rowA1 = (t + 256) >> 2, ko1 = ((t + 256) & 3) * 8;

  for (int kt = 0; kt < K; kt += 32) {
    if constexpr (AM == 1) {
      const u16* A = (const u16*)Ap;
      gload16(A + (size_t)(m0 + rowA0) * K + kt + ko0, (char*)As + (size_t)w * 1024);
      gload16(A + (size_t)(m0 + rowA1) * K + kt + ko1, (char*)As + (size_t)(w + 4) * 1024);
    } else {
      const float* A = (const float*)Ap;
      *(bf16x8*)((char*)As + (size_t)t * 16) = cvt8(A + (size_t)(m0 + rowA0) * K + kt + ko0);
      *(bf16x8*)((char*)As + (size_t)(t + 256) * 16) = cvt8(A + (size_t)(m0 + rowA1) * K + kt + ko1);
    }
    if constexpr (WM == 1) {
      const u16* W = (const u16*)Wp;
      gload16(W + (size_t)(n0 + rowA0) * K + kt + ko0, (char*)Bs + (size_t)w * 1024);
      gload16(W + (size_t)(n0 + rowA1) * K + kt + ko1, (char*)Bs + (size_t)(w + 4) * 1024);
    } else {
      const float* W = (const float*)Wp;
      *(bf16x8*)((char*)Bs + (size_t)t * 16) = cvt8(W + (size_t)(n0 + rowA0) * K + kt + ko0);
      *(bf16x8*)((char*)Bs + (size_t)(t + 256) * 16) = cvt8(W + (size_t)(n0 + rowA1) * K + kt + ko1);
    }
    __syncthreads();

    bf16x8 af[4], bw[4];
#pragma unroll
    for (int i = 0; i < 4; ++i) {
      af[i] = *(const bf16x8*)(As + (size_t)(wr * 64 + i * 16 + lr) * 32 + lg * 8);
      bw[i] = *(const bf16x8*)(Bs + (size_t)(wc * 64 + i * 16 + lr) * 32 + lg * 8);
    }
#pragma unroll
    for (int i = 0; i < 4; ++i)
#pragma unroll
      for (int j = 0; j < 4; ++j)
        acc[i][j] = mfma16(af[i], bw[j], acc[i][j]);
    __syncthreads();
  }

#pragma unroll
  for (int i = 0; i < 4; ++i) {
#pragma unroll
    for (int j = 0; j < 4; ++j) {
      const int col = n0 + wc * 64 + j * 16 + lr;
      const float bv = bias[col];
      const int row = m0 + wr * 64 + i * 16 + lg * 4;
#pragma unroll
      for (int r = 0; r < 4; ++r) {
        if constexpr (CM == 1)
          ((float*)Cp)[(size_t)(row + r) * ldc + col] = acc[i][j][r] + bv;
        else
          ((u16*)Cp)[(size_t)(row + r) * ldc + col] = f2bf(acc[i][j][r] + bv);
      }
    }
  }
}

__global__ __launch_bounds__(256) void k_gemm_out_bb(
    const u16* __restrict__ ao, const u16* __restrict__ wob,
    const float* __restrict__ bo, float* __restrict__ out) {
  gemm_body<1, 1, 1>(ao, wob, bo, out, D_);
}

__global__ __launch_bounds__(256) void k_gemm_qkv_xb(
    const u16* __restrict__ xb, const float* __restrict__ wq,
    const float* __restrict__ bq, const float* __restrict__ wk,
    const float* __restrict__ bk, const float* __restrict__ wv,
    const float* __restrict__ bv, u16* __restrict__ q, u16* __restrict__ k,
    u16* __restrict__ v) {
  const int z = blockIdx.z;
  const float* W = z == 0 ? wq : (z == 1 ? wk : wv);
  const float* bias = z == 0 ? bq : (z == 1 ? bk : bv);
  u16* C = z == 0 ? q : (z == 1 ? k : v);
  gemm_body<1, 0, 0>(xb, W, bias, C, D_);
}

__global__ __launch_bounds__(256) void k_gemm_out(const u16* __restrict__ ao,
                                                  const float* __restrict__ wo,
                                                  const float* __restrict__ bo,
                                                  float* __restrict__ out) {
  gemm_body<1, 0, 1>(ao, wo, bo, out, D_);
}

__global__ __launch_bounds__(256) void k_gemm_qkv_g(
    const float* __restrict__ x, const float* __restrict__ wq,
    const float* __restrict__ bq, const float* __restrict__ wk,
    const float* __restrict__ bk, const float* __restrict__ wv,
    const float* __restrict__ bv, u16* __restrict__ qg, u16* __restrict__ kg,
    u16* __restrict__ vg, int g) {
  const int z = blockIdx.z;
  const float* W = (z == 0 ? wq : (z == 1 ? wk : wv)) + (size_t)g * GW * D_;
  const float* bias = (z == 0 ? bq : (z == 1 ? bk : bv)) + g * GW;
  u16* C = z == 0 ? qg : (z == 1 ? kg : vg);
  gemm_body<0, 0, 0>(x, W, bias, C, GW);
}

// ---------------- RoPE (interleaved) in place, for tiers without table space
__device__ __forceinline__ void rope_one(u16* p, float cv, float sv) {
  unsigned u = *(const unsigned*)p;
  float x1 = bf2f((u16)(u & 0xffff)), x2 = bf2f((u16)(u >> 16));
  unsigned r = (unsigned)f2bf(x1 * cv - x2 * sv) |
               ((unsigned)f2bf(x1 * sv + x2 * cv) << 16);
  *(unsigned*)p = r;
}

__global__ void k_rope_full(u16* q, u16* kk) {
  const int idx = blockIdx.x * 256 + threadIdx.x;
  const int i = idx & 63;
  const int hh = (idx >> 6) & 15;
  const int bs = idx >> 10;
  const int s = bs & (S_ - 1);
  const float freq = expf(-(float)i * 0.14391157f);
  float sv, cv;
  sincosf((float)s * freq, &sv, &cv);
  const size_t off = (size_t)bs * D_ + (size_t)hh * HD_ + 2 * i;
  rope_one(q + off, cv, sv);
  rope_one(kk + off, cv, sv);
}

__global__ void k_rope_g(u16* q, u16* kk) {
  const int idx = blockIdx.x * 256 + threadIdx.x;
  const int i = idx & 63;
  const int hh = (idx >> 6) & 3;
  const int bs = idx >> 8;
  const int s = bs & (S_ - 1);
  const float freq = expf(-(float)i * 0.14391157f);
  float sv, cv;
  sincosf((float)s * freq, &sv, &cv);
  const size_t off = (size_t)bs * GW + (size_t)hh * HD_ + 2 * i;
  rope_one(q + off, cv, sv);
  rope_one(kk + off, cv, sv);
}

// ---------------- Flash attention (causal), swapped-QK^T, double-buffered
// K/V with counted vmcnt + raw barriers. O may alias Q (disjoint regions).
__device__ __forceinline__ void attn_body(const u16* Q, const u16* Kd,
                                          const u16* V, u16* O,
                                          size_t base_in, size_t base_out,
                                          int ld_in, int ld_out, int q0) {
  const int t = threadIdx.x, w = t >> 6, l = t & 63, lr = l & 15, lg = l >> 4;

  __shared__ u16 Ks[2][KB * HD_];   // 2 x [64][128], chunk-XOR swizzled
  __shared__ u16 Vt[2][HD_ * VST];  // 2 x transposed [128][72]
  __shared__ u16 Ps[4][16 * PST];   // per-wave P tile

  bf16x8 qf[4];
  {
    const u16* qp = Q + base_in + (size_t)(q0 + w * 16 + lr) * ld_in;
#pragma unroll
    for (int ds = 0; ds < 4; ++ds)
      qf[ds] = *(const bf16x8*)(qp + ds * 32 + lg * 8);
  }

  f32x4 oacc[8];
#pragma unroll
  for (int f = 0; f < 8; ++f) oacc[f] = f32x4{0.f, 0.f, 0.f, 0.f};
  float mrow = -1e30f, lrow = 0.f;

  const int qrow = q0 + w * 16 + lr;
  const int nt = q0 / KB + 1;
  const float sc = 0.08838834764831845f;  // 1/sqrt(128)

  const int c1 = t + 256;
  const int kk20 = (t & 31) * 2, d00 = (t >> 5) * 8;
  const int kk21 = (c1 & 31) * 2, d01 = (c1 >> 5) * 8;

  bf16x8 vc[4];

  // ---- prologue: stage tile 0
#pragma unroll
  for (int r = 0; r < 4; ++r) {
    const int c = t + 256 * r;
    const int row = c >> 4, c16 = c & 15;
    const int gc = c16 ^ (row & 7);
    gload16(Kd + base_in + (size_t)row * ld_in + gc * 8,
            (char*)Ks[0] + (size_t)(w + 4 * r) * 1024);
  }
  vc[0] = *(const bf16x8*)(V + base_in + (size_t)kk20 * ld_in + d00);
  vc[1] = *(const bf16x8*)(V + base_in + (size_t)(kk20 + 1) * ld_in + d00);
  vc[2] = *(const bf16x8*)(V + base_in + (size_t)kk21 * ld_in + d01);
  vc[3] = *(const bf16x8*)(V + base_in + (size_t)(kk21 + 1) * ld_in + d01);

  for (int tt = 0; tt < nt; ++tt) {
    const int cur = tt & 1;
    const int kv0 = tt * KB;
    const bool more = (tt + 1 < nt);

    if (more) {
      const int kvn = kv0 + KB;
#pragma unroll
      for (int r = 0; r < 4; ++r) {
        const int c = t + 256 * r;
        const int row = c >> 4, c16 = c & 15;
        const int gc = c16 ^ (row & 7);
        gload16(Kd + base_in + (size_t)(kvn + row) * ld_in + gc * 8,
                (char*)Ks[cur ^ 1] + (size_t)(w + 4 * r) * 1024);
      }
      asm volatile("s_waitcnt vmcnt(4)" ::: "memory");
    } else {
      asm volatile("s_waitcnt vmcnt(0)" ::: "memory");
    }
    __builtin_amdgcn_sched_barrier(0);

    {
      u16* vt = Vt[cur];
#pragma unroll
      for (int j = 0; j < 8; ++j) {
        unsigned p0 = (unsigned)(unsigned short)vc[0][j] |
                      ((unsigned)(unsigned short)vc[1][j] << 16);
        *(unsigned*)&vt[(size_t)(d00 + j) * VST + kk20] = p0;
        unsigned p1 = (unsigned)(unsigned short)vc[2][j] |
                      ((unsigned)(unsigned short)vc[3][j] << 16);
        *(unsigned*)&vt[(size_t)(d01 + j) * VST + kk21] = p1;
      }
    }
    if (more) {
      const int kvn = kv0 + KB;
      vc[0] = *(const bf16x8*)(V + base_in + (size_t)(kvn + kk20) * ld_in + d00);
      vc[1] = *(const bf16x8*)(V + base_in + (size_t)(kvn + kk20 + 1) * ld_in + d00);
      vc[2] = *(const bf16x8*)(V + base_in + (size_t)(kvn + kk21) * ld_in + d01);
      vc[3] = *(const bf16x8*)(V + base_in + (size_t)(kvn + kk21 + 1) * ld_in + d01);
    }
    asm volatile("s_waitcnt lgkmcnt(0)" ::: "memory");
    __builtin_amdgcn_sched_barrier(0);
    __builtin_amdgcn_s_barrier();
    __builtin_amdgcn_sched_barrier(0);

    float p[16];
    __builtin_amdgcn_s_setprio(1);
#pragma unroll
    for (int h = 0; h < 4; ++h) {
      f32x4 s = {0.f, 0.f, 0.f, 0.f};
#pragma unroll
      for (int ds = 0; ds < 4; ++ds) {
        const int ch = (ds * 4 + lg) ^ (lr & 7);
        bf16x8 kf = *(const bf16x8*)(Ks[cur] + (size_t)(h * 16 + lr) * HD_ + ch * 8);
        s = mfma16(kf, qf[ds], s);
      }
#pragma unroll
      for (int r = 0; r < 4; ++r) p[h * 4 + r] = s[r] * sc;
    }
    __builtin_amdgcn_s_setprio(0);
    if (kv0 + KB - 1 > q0 + w * 16) {
#pragma unroll
      for (int h = 0; h < 4; ++h)
#pragma unroll
        for (int r = 0; r < 4; ++r)
          if (kv0 + h * 16 + lg * 4 + r > qrow) p[h * 4 + r] = -1e30f;
    }
    float pm = p[0];
#pragma unroll
    for (int i = 1; i < 16; ++i) pm = fmaxf(pm, p[i]);
    pm = fmaxf(pm, __shfl_xor(pm, 16, 64));
    pm = fmaxf(pm, __shfl_xor(pm, 32, 64));
    const float mn = fmaxf(mrow, pm);
    const float scl = __expf(mrow - mn);
    mrow = mn;
    float rs = 0.f;
#pragma unroll
    for (int i = 0; i < 16; ++i) {
      p[i] = __expf(p[i] - mn);
      rs += p[i];
    }
    rs += __shfl_xor(rs, 16, 64);
    rs += __shfl_xor(rs, 32, 64);
    lrow = lrow * scl + rs;
    float sj[4];
#pragma unroll
    for (int j = 0; j < 4; ++j) sj[j] = __shfl(scl, lg * 4 + j, 64);
#pragma unroll
    for (int f = 0; f < 8; ++f)
#pragma unroll
      for (int j = 0; j < 4; ++j) oacc[f][j] *= sj[j];
#pragma unroll
    for (int h = 0; h < 4; ++h)
#pragma unroll
      for (int r = 0; r < 4; ++r)
        Ps[w][lr * PST + h * 16 + lg * 4 + r] = f2bf(p[h * 4 + r]);
    bf16x8 pf0 = *(const bf16x8*)&Ps[w][lr * PST + lg * 8];
    bf16x8 pf1 = *(const bf16x8*)&Ps[w][lr * PST + 32 + lg * 8];
    __builtin_amdgcn_s_setprio(1);
#pragma unroll
    for (int f = 0; f < 8; ++f) {
      bf16x8 vf0 = *(const bf16x8*)&Vt[cur][(size_t)(f * 16 + lr) * VST + lg * 8];
      bf16x8 vf1 = *(const bf16x8*)&Vt[cur][(size_t)(f * 16 + lr) * VST + 32 + lg * 8];
      oacc[f] = mfma16(pf0, vf0, oacc[f]);
      oacc[f] = mfma16(pf1, vf1, oacc[f]);
    }
    __builtin_amdgcn_s_setprio(0);
    __builtin_amdgcn_sched_barrier(0);
    __builtin_amdgcn_s_barrier();
    __builtin_amdgcn_sched_barrier(0);
  }

  const float inv = 1.0f / lrow;
  float ij[4];
#pragma unroll
  for (int j = 0; j < 4; ++j) ij[j] = __shfl(inv, lg * 4 + j, 64);
  u16* Op = O + base_out;
#pragma unroll
  for (int f = 0; f < 8; ++f)
#pragma unroll
    for (int j = 0; j < 4; ++j)
      Op[(size_t)(q0 + w * 16 + lg * 4 + j) * ld_out + f * 16 + lr] =
          f2bf(oacc[f][j] * ij[j]);
}

// merged, triangular-paired: uniform work/block; XCD-chunked remap.
__global__ __launch_bounds__(256) void k_attn_full(const u16* Q, const u16* Kd,
                                                   const u16* V, u16* O) {
  const int lin = blockIdx.y * gridDim.x + blockIdx.x;  // grid (16, 32) = 512
  const int work = (lin & 7) * 64 + (lin >> 3);
  const int bh = work >> 4;
  const int pr = work & 15;
  const int b = bh >> 4, h = bh & 15;
  const size_t base = ((size_t)b * S_) * D_ + (size_t)h * HD_;
  attn_body(Q, Kd, V, O, base, base, D_, D_, 64 * (31 - pr));
  attn_body(Q, Kd, V, O, base, base, D_, D_, 64 * pr);
}

// grouped fallback
__global__ __launch_bounds__(256) void k_attn_g(const u16* __restrict__ Q,
                                                const u16* __restrict__ Kd,
                                                const u16* __restrict__ V,
                                                u16* __restrict__ O, int g) {
  const int by = blockIdx.y;
  const int b = by >> 2, hh = by & 3;
  const size_t base_in = ((size_t)b * S_) * GW + (size_t)hh * HD_;
  const size_t base_out = ((size_t)b * S_) * D_ + (size_t)(g * 4 + hh) * HD_;
  attn_body(Q, Kd, V, O, base_in, base_out, GW, D_, blockIdx.x * 64);
}

extern "C" void kernel_launch(void* const* d_in, const int* in_sizes, int n_in,
                              void* d_out, int out_size, void* d_ws,
                              size_t ws_size, hipStream_t stream) {
  (void)in_sizes; (void)n_in; (void)out_size;
  const float* x = (const float*)d_in[0];
  const float* wq = (const float*)d_in[1];
  const float* bq = (const float*)d_in[2];
  const float* wk = (const float*)d_in[3];
  const float* bk = (const float*)d_in[4];
  const float* wv = (const float*)d_in[5];
  const float* bv = (const float*)d_in[6];
  const float* wo = (const float*)d_in[7];
  const float* bo = (const float*)d_in[8];
  float* out = (float*)d_out;

  const size_t XB = (size_t)B_ * S_ * D_ * 2;  // 16,777,216
  const size_t WB3 = 3 * (size_t)D_ * D_ * 2;  // 25,165,824
  const size_t WB1 = (size_t)D_ * D_ * 2;      // 8,388,608
  const size_t TB = (size_t)S_ * 64 * 8;       // 1,048,576 rope table
  char* ws = (char*)d_ws;
  char* ob = (char*)d_out;

  u16 *xb, *q, *k, *v, *wqkvb = nullptr, *wob = nullptr;
  float2* tab = nullptr;
  int tier;
  if (ws_size >= 4 * XB + WB3 + WB1 + TB) {
    xb = (u16*)ws; q = (u16*)(ws + XB); k = (u16*)(ws + 2 * XB);
    v = (u16*)(ws + 3 * XB);
    wqkvb = (u16*)(ws + 4 * XB); wob = (u16*)(ws + 4 * XB + WB3);
    tab = (float2*)(ws + 4 * XB + WB3 + WB1);
    tier = 1;
  } else if (ws_size >= 3 * XB + WB3 + WB1 + TB) {
    xb = (u16*)ob;
    q = (u16*)ws; k = (u16*)(ws + XB); v = (u16*)(ws + 2 * XB);
    wqkvb = (u16*)(ws + 3 * XB); wob = (u16*)(ws + 3 * XB + WB3);
    tab = (float2*)(ws + 3 * XB + WB3 + WB1);
    tier = 1;
  } else if (ws_size >= 2 * XB + WB3 + TB) {
    xb = (u16*)ob; v = (u16*)(ob + XB);
    q = (u16*)ws; k = (u16*)(ws + XB);
    wqkvb = (u16*)(ws + 2 * XB);
    tab = (float2*)(ws + 2 * XB + WB3);
    tier = 2;
  } else if (ws_size >= 2 * XB) {
    xb = (u16*)ob; v = (u16*)(ob + XB);
    q = (u16*)ws; k = (u16*)(ws + XB);
    tier = 3;
  } else {
    tier = 4;
  }

  if (tier == 1 || tier == 2) {
    dim3 gc(4096, 6);
    k_cvt_all<<<gc, 256, 0, stream>>>(x, wq, wk, wv, wo, xb, wqkvb, wob, tab);
    dim3 g1(8, 32, 3);
    k_gemm_qkv_128x256<<<g1, 512, 0, stream>>>(xb, wqkvb, bq, bk, bv, q, k, v, tab);
    dim3 g2(16, 32);
    k_attn_full<<<g2, 256, 0, stream>>>(q, k, v, q);
    dim3 g3(16, 32);
    if (tier == 1)
      k_gemm_out_bb<<<g3, 256, 0, stream>>>(q, wob, bo, out);
    else
      k_gemm_out<<<g3, 256, 0, stream>>>(q, wo, bo, out);
  } else if (tier == 3) {
    dim3 gc(4096, 1);
    k_cvt_all<<<gc, 256, 0, stream>>>(x, wq, wk, wv, wo, xb, xb, nullptr, nullptr);
    dim3 g1(16, 32, 3);
    k_gemm_qkv_xb<<<g1, 256, 0, stream>>>(xb, wq, bq, wk, bk, wv, bv, q, k, v);
    k_rope_full<<<16384, 256, 0, stream>>>(q, k);
    dim3 g2(16, 32);
    k_attn_full<<<g2, 256, 0, stream>>>(q, k, v, q);
    dim3 g3(16, 32);
    k_gemm_out<<<g3, 256, 0, stream>>>(q, wo, bo, out);
  } else {
    u16* qg = (u16*)ob;
    u16* kg = qg + (size_t)(B_ * S_) * GW;
    u16* vg = kg + (size_t)(B_ * S_) * GW;
    u16* ao = (u16*)ws;
    for (int g = 0; g < 4; ++g) {
      dim3 g1(4, 32, 3);
      k_gemm_qkv_g<<<g1, 256, 0, stream>>>(x, wq, bq, wk, bk, wv, bv, qg, kg, vg, g);
      k_rope_g<<<4096, 256, 0, stream>>>(qg, kg);
      dim3 g2(32, 8);
      k_attn_g<<<g2, 256, 0, stream>>>(qg, kg, vg, ao, g);
    }
    dim3 g3(16, 32);
    k_gemm_out<<<g3, 256, 0, stream>>>(ao, wo, bo, out);
  }
}

// Round 14
// 276.566 us; speedup vs baseline: 1.1646x; 1.1646x over previous
//
#include <hip/hip_runtime.h>

typedef unsigned short u16;
typedef short bf16x8 __attribute__((ext_vector_type(8)));
typedef float f32x4 __attribute__((ext_vector_type(4)));

#define B_ 2
#define S_ 2048
#define D_ 2048
#define HD_ 128
#define GW 512   // head-group width for fallback path
#define KB 64    // attention KV tile rows
#define VST 72   // Vt row stride (u16)
#define PST 72   // Ps row stride (u16)

__device__ __forceinline__ float bf2f(u16 h) {
  unsigned u = ((unsigned)h) << 16;
  return __builtin_bit_cast(float, u);
}
__device__ __forceinline__ u16 f2bf(float f) {
  unsigned u = __builtin_bit_cast(unsigned, f);
  u += 0x7FFF + ((u >> 16) & 1);
  return (u16)(u >> 16);
}
__device__ __forceinline__ bf16x8 cvt8(const float* p) {
  float4 a = *(const float4*)p;
  float4 b = *(const float4*)(p + 4);
  bf16x8 r;
  r[0] = (short)f2bf(a.x); r[1] = (short)f2bf(a.y);
  r[2] = (short)f2bf(a.z); r[3] = (short)f2bf(a.w);
  r[4] = (short)f2bf(b.x); r[5] = (short)f2bf(b.y);
  r[6] = (short)f2bf(b.z); r[7] = (short)f2bf(b.w);
  return r;
}

__device__ __forceinline__ void gload16(const void* g, void* lds) {
  __builtin_amdgcn_global_load_lds(
      (const __attribute__((address_space(1))) unsigned*)g,
      (__attribute__((address_space(3))) unsigned*)lds, 16, 0, 0);
}

__device__ __forceinline__ f32x4 mfma16(bf16x8 a, bf16x8 b, f32x4 c) {
  return __builtin_amdgcn_mfma_f32_16x16x32_bf16(a, b, c, 0, 0, 0);
}

// ---------------- f32 -> bf16 bulk convert + RoPE table. Grid (4096, ny).
__global__ void k_cvt_all(const float* __restrict__ x, const float* __restrict__ wq,
                          const float* __restrict__ wk, const float* __restrict__ wv,
                          const float* __restrict__ wo, u16* __restrict__ xb,
                          u16* __restrict__ wqkvb, u16* wob, float2* tab) {
  const int slice = blockIdx.y;
  const int i = blockIdx.x * 256 + threadIdx.x;
  if (slice == 5) {
    if (tab != nullptr && i < 131072) {  // 2048 x 64
      const int s = i >> 6, ip = i & 63;
      const float freq = expf(-(float)ip * 0.14391157f);  // ln(10000)/64
      float sv, cv;
      sincosf((float)s * freq, &sv, &cv);
      tab[i] = make_float2(cv, sv);
    }
    return;
  }
  if (slice == 4 && wob == nullptr) return;
  const float* src;
  u16* dst;
  int n8;
  if (slice == 0) { src = x; dst = xb; n8 = 1048576; }
  else if (slice == 1) { src = wq; dst = wqkvb; n8 = 524288; }
  else if (slice == 2) { src = wk; dst = wqkvb + 4194304; n8 = 524288; }
  else if (slice == 3) { src = wv; dst = wqkvb + 8388608; n8 = 524288; }
  else { src = wo; dst = wob; n8 = 524288; }
  if (i < n8) *(bf16x8*)(dst + (size_t)i * 8) = cvt8(src + (size_t)i * 8);
}

// ---------------- m97-structure GEMM (proven 138us for QKV w/ fused rope).
// AM/WM: 1 = bf16 via global_load_lds, 0 = f32 reg-stage+cvt. CM: 0 bf16/1 f32.
// tab != nullptr (CM=0 only): apply interleaved RoPE in epilogue.
template <int AM, int WM, int CM>
__device__ __forceinline__ void gemm_body(const void* Ap, const void* Wp,
                                          const float* __restrict__ bias,
                                          void* Cp, int ldc,
                                          const float2* __restrict__ tab) {
  constexpr int K = 2048;
  __shared__ u16 As[128 * 32];
  __shared__ u16 Bs[128 * 32];
  const int t = threadIdx.x;
  const int w = t >> 6, l = t & 63, lr = l & 15, lg = l >> 4;
  const int m0 = blockIdx.y * 128, n0 = blockIdx.x * 128;
  const int wr = w >> 1, wc = w & 1;

  f32x4 acc[4][4];
#pragma unroll
  for (int i = 0; i < 4; ++i)
#pragma unroll
    for (int j = 0; j < 4; ++j) acc[i][j] = f32x4{0.f, 0.f, 0.f, 0.f};

  const int rowA0 = t >> 2, ko0 = (t & 3) * 8;
  const int rowA1 = (t + 256) >> 2, ko1 = ((t + 256) & 3) * 8;

  for (int kt = 0; kt < K; kt += 32) {
    if constexpr (AM == 1) {
      const u16* A = (const u16*)Ap;
      gload16(A + (size_t)(m0 + rowA0) * K + kt + ko0, (char*)As + (size_t)w * 1024);
      gload16(A + (size_t)(m0 + rowA1) * K + kt + ko1, (char*)As + (size_t)(w + 4) * 1024);
    } else {
      const float* A = (const float*)Ap;
      *(bf16x8*)((char*)As + (size_t)t * 16) = cvt8(A + (size_t)(m0 + rowA0) * K + kt + ko0);
      *(bf16x8*)((char*)As + (size_t)(t + 256) * 16) = cvt8(A + (size_t)(m0 + rowA1) * K + kt + ko1);
    }
    if constexpr (WM == 1) {
      const u16* W = (const u16*)Wp;
      gload16(W + (size_t)(n0 + rowA0) * K + kt + ko0, (char*)Bs + (size_t)w * 1024);
      gload16(W + (size_t)(n0 + rowA1) * K + kt + ko1, (char*)Bs + (size_t)(w + 4) * 1024);
    } else {
      const float* W = (const float*)Wp;
      *(bf16x8*)((char*)Bs + (size_t)t * 16) = cvt8(W + (size_t)(n0 + rowA0) * K + kt + ko0);
      *(bf16x8*)((char*)Bs + (size_t)(t + 256) * 16) = cvt8(W + (size_t)(n0 + rowA1) * K + kt + ko1);
    }
    __syncthreads();

    bf16x8 af[4], bw[4];
#pragma unroll
    for (int i = 0; i < 4; ++i) {
      af[i] = *(const bf16x8*)(As + (size_t)(wr * 64 + i * 16 + lr) * 32 + lg * 8);
      bw[i] = *(const bf16x8*)(Bs + (size_t)(wc * 64 + i * 16 + lr) * 32 + lg * 8);
    }
#pragma unroll
    for (int i = 0; i < 4; ++i)
#pragma unroll
      for (int j = 0; j < 4; ++j)
        acc[i][j] = mfma16(af[i], bw[j], acc[i][j]);
    __syncthreads();
  }

#pragma unroll
  for (int i = 0; i < 4; ++i) {
#pragma unroll
    for (int j = 0; j < 4; ++j) {
      const int col = n0 + wc * 64 + j * 16 + lr;
      const float bv = bias[col];
      const int row = m0 + wr * 64 + i * 16 + lg * 4;
      if (CM == 0 && tab != nullptr) {
        const int ip = (col & 127) >> 1;
        const int odd = col & 1;
#pragma unroll
        for (int r = 0; r < 4; ++r) {
          const float v = acc[i][j][r] + bv;
          const float p = __shfl_xor(v, 1, 64);
          const float2 cs = tab[((row + r) & (S_ - 1)) * 64 + ip];
          const float o = odd ? (p * cs.y + v * cs.x) : (v * cs.x - p * cs.y);
          ((u16*)Cp)[(size_t)(row + r) * ldc + col] = f2bf(o);
        }
      } else {
#pragma unroll
        for (int r = 0; r < 4; ++r) {
          if constexpr (CM == 1)
            ((float*)Cp)[(size_t)(row + r) * ldc + col] = acc[i][j][r] + bv;
          else
            ((u16*)Cp)[(size_t)(row + r) * ldc + col] = f2bf(acc[i][j][r] + bv);
        }
      }
    }
  }
}

__global__ __launch_bounds__(256) void k_gemm_qkv_bb(
    const u16* __restrict__ xb, const u16* __restrict__ wqkvb,
    const float* __restrict__ bq, const float* __restrict__ bk,
    const float* __restrict__ bv, u16* __restrict__ q, u16* __restrict__ k,
    u16* __restrict__ v, const float2* __restrict__ tab) {
  const int z = blockIdx.z;
  const u16* W = wqkvb + (size_t)z * D_ * D_;
  const float* bias = z == 0 ? bq : (z == 1 ? bk : bv);
  u16* C = z == 0 ? q : (z == 1 ? k : v);
  gemm_body<1, 1, 0>(xb, W, bias, C, D_, z == 2 ? nullptr : tab);
}

__global__ __launch_bounds__(256) void k_gemm_out_bb(
    const u16* __restrict__ ao, const u16* __restrict__ wob,
    const float* __restrict__ bo, float* __restrict__ out) {
  gemm_body<1, 1, 1>(ao, wob, bo, out, D_, nullptr);
}

__global__ __launch_bounds__(256) void k_gemm_qkv_xb(
    const u16* __restrict__ xb, const float* __restrict__ wq,
    const float* __restrict__ bq, const float* __restrict__ wk,
    const float* __restrict__ bk, const float* __restrict__ wv,
    const float* __restrict__ bv, u16* __restrict__ q, u16* __restrict__ k,
    u16* __restrict__ v) {
  const int z = blockIdx.z;
  const float* W = z == 0 ? wq : (z == 1 ? wk : wv);
  const float* bias = z == 0 ? bq : (z == 1 ? bk : bv);
  u16* C = z == 0 ? q : (z == 1 ? k : v);
  gemm_body<1, 0, 0>(xb, W, bias, C, D_, nullptr);
}

__global__ __launch_bounds__(256) void k_gemm_out(const u16* __restrict__ ao,
                                                  const float* __restrict__ wo,
                                                  const float* __restrict__ bo,
                                                  float* __restrict__ out) {
  gemm_body<1, 0, 1>(ao, wo, bo, out, D_, nullptr);
}

__global__ __launch_bounds__(256) void k_gemm_qkv_g(
    const float* __restrict__ x, const float* __restrict__ wq,
    const float* __restrict__ bq, const float* __restrict__ wk,
    const float* __restrict__ bk, const float* __restrict__ wv,
    const float* __restrict__ bv, u16* __restrict__ qg, u16* __restrict__ kg,
    u16* __restrict__ vg, int g) {
  const int z = blockIdx.z;
  const float* W = (z == 0 ? wq : (z == 1 ? wk : wv)) + (size_t)g * GW * D_;
  const float* bias = (z == 0 ? bq : (z == 1 ? bk : bv)) + g * GW;
  u16* C = z == 0 ? qg : (z == 1 ? kg : vg);
  gemm_body<0, 0, 0>(x, W, bias, C, GW, nullptr);
}

// ---------------- RoPE (interleaved) in place, for tiers without table space
__device__ __forceinline__ void rope_one(u16* p, float cv, float sv) {
  unsigned u = *(const unsigned*)p;
  float x1 = bf2f((u16)(u & 0xffff)), x2 = bf2f((u16)(u >> 16));
  unsigned r = (unsigned)f2bf(x1 * cv - x2 * sv) |
               ((unsigned)f2bf(x1 * sv + x2 * cv) << 16);
  *(unsigned*)p = r;
}

__global__ void k_rope_full(u16* q, u16* kk) {
  const int idx = blockIdx.x * 256 + threadIdx.x;
  const int i = idx & 63;
  const int hh = (idx >> 6) & 15;
  const int bs = idx >> 10;
  const int s = bs & (S_ - 1);
  const float freq = expf(-(float)i * 0.14391157f);
  float sv, cv;
  sincosf((float)s * freq, &sv, &cv);
  const size_t off = (size_t)bs * D_ + (size_t)hh * HD_ + 2 * i;
  rope_one(q + off, cv, sv);
  rope_one(kk + off, cv, sv);
}

__global__ void k_rope_g(u16* q, u16* kk) {
  const int idx = blockIdx.x * 256 + threadIdx.x;
  const int i = idx & 63;
  const int hh = (idx >> 6) & 3;
  const int bs = idx >> 8;
  const int s = bs & (S_ - 1);
  const float freq = expf(-(float)i * 0.14391157f);
  float sv, cv;
  sincosf((float)s * freq, &sv, &cv);
  const size_t off = (size_t)bs * GW + (size_t)hh * HD_ + 2 * i;
  rope_one(q + off, cv, sv);
  rope_one(kk + off, cv, sv);
}

// ---------------- Flash attention (causal), swapped-QK^T, double-buffered.
// attn_body: single-q-tile version (kept for grouped fallback).
__device__ __forceinline__ void attn_body(const u16* Q, const u16* Kd,
                                          const u16* V, u16* O,
                                          size_t base_in, size_t base_out,
                                          int ld_in, int ld_out, int q0) {
  const int t = threadIdx.x, w = t >> 6, l = t & 63, lr = l & 15, lg = l >> 4;

  __shared__ u16 Ks[2][KB * HD_];
  __shared__ u16 Vt[2][HD_ * VST];
  __shared__ u16 Ps[4][16 * PST];

  bf16x8 qf[4];
  {
    const u16* qp = Q + base_in + (size_t)(q0 + w * 16 + lr) * ld_in;
#pragma unroll
    for (int ds = 0; ds < 4; ++ds)
      qf[ds] = *(const bf16x8*)(qp + ds * 32 + lg * 8);
  }

  f32x4 oacc[8];
#pragma unroll
  for (int f = 0; f < 8; ++f) oacc[f] = f32x4{0.f, 0.f, 0.f, 0.f};
  float mrow = -1e30f, lrow = 0.f;

  const int qrow = q0 + w * 16 + lr;
  const int nt = q0 / KB + 1;
  const float sc = 0.08838834764831845f;

  const int c1 = t + 256;
  const int kk20 = (t & 31) * 2, d00 = (t >> 5) * 8;
  const int kk21 = (c1 & 31) * 2, d01 = (c1 >> 5) * 8;

  bf16x8 vc[4];

#pragma unroll
  for (int r = 0; r < 4; ++r) {
    const int c = t + 256 * r;
    const int row = c >> 4, c16 = c & 15;
    const int gc = c16 ^ (row & 7);
    gload16(Kd + base_in + (size_t)row * ld_in + gc * 8,
            (char*)Ks[0] + (size_t)(w + 4 * r) * 1024);
  }
  vc[0] = *(const bf16x8*)(V + base_in + (size_t)kk20 * ld_in + d00);
  vc[1] = *(const bf16x8*)(V + base_in + (size_t)(kk20 + 1) * ld_in + d00);
  vc[2] = *(const bf16x8*)(V + base_in + (size_t)kk21 * ld_in + d01);
  vc[3] = *(const bf16x8*)(V + base_in + (size_t)(kk21 + 1) * ld_in + d01);

  for (int tt = 0; tt < nt; ++tt) {
    const int cur = tt & 1;
    const int kv0 = tt * KB;
    const bool more = (tt + 1 < nt);

    if (more) {
      const int kvn = kv0 + KB;
#pragma unroll
      for (int r = 0; r < 4; ++r) {
        const int c = t + 256 * r;
        const int row = c >> 4, c16 = c & 15;
        const int gc = c16 ^ (row & 7);
        gload16(Kd + base_in + (size_t)(kvn + row) * ld_in + gc * 8,
                (char*)Ks[cur ^ 1] + (size_t)(w + 4 * r) * 1024);
      }
      asm volatile("s_waitcnt vmcnt(4)" ::: "memory");
    } else {
      asm volatile("s_waitcnt vmcnt(0)" ::: "memory");
    }
    __builtin_amdgcn_sched_barrier(0);

    {
      u16* vt = Vt[cur];
#pragma unroll
      for (int j = 0; j < 8; ++j) {
        unsigned p0 = (unsigned)(unsigned short)vc[0][j] |
                      ((unsigned)(unsigned short)vc[1][j] << 16);
        *(unsigned*)&vt[(size_t)(d00 + j) * VST + kk20] = p0;
        unsigned p1 = (unsigned)(unsigned short)vc[2][j] |
                      ((unsigned)(unsigned short)vc[3][j] << 16);
        *(unsigned*)&vt[(size_t)(d01 + j) * VST + kk21] = p1;
      }
    }
    if (more) {
      const int kvn = kv0 + KB;
      vc[0] = *(const bf16x8*)(V + base_in + (size_t)(kvn + kk20) * ld_in + d00);
      vc[1] = *(const bf16x8*)(V + base_in + (size_t)(kvn + kk20 + 1) * ld_in + d00);
      vc[2] = *(const bf16x8*)(V + base_in + (size_t)(kvn + kk21) * ld_in + d01);
      vc[3] = *(const bf16x8*)(V + base_in + (size_t)(kvn + kk21 + 1) * ld_in + d01);
    }
    asm volatile("s_waitcnt lgkmcnt(0)" ::: "memory");
    __builtin_amdgcn_sched_barrier(0);
    __builtin_amdgcn_s_barrier();
    __builtin_amdgcn_sched_barrier(0);

    float p[16];
    __builtin_amdgcn_s_setprio(1);
#pragma unroll
    for (int h = 0; h < 4; ++h) {
      f32x4 s = {0.f, 0.f, 0.f, 0.f};
#pragma unroll
      for (int ds = 0; ds < 4; ++ds) {
        const int ch = (ds * 4 + lg) ^ (lr & 7);
        bf16x8 kf = *(const bf16x8*)(Ks[cur] + (size_t)(h * 16 + lr) * HD_ + ch * 8);
        s = mfma16(kf, qf[ds], s);
      }
#pragma unroll
      for (int r = 0; r < 4; ++r) p[h * 4 + r] = s[r] * sc;
    }
    __builtin_amdgcn_s_setprio(0);
    if (kv0 + KB - 1 > q0 + w * 16) {
#pragma unroll
      for (int h = 0; h < 4; ++h)
#pragma unroll
        for (int r = 0; r < 4; ++r)
          if (kv0 + h * 16 + lg * 4 + r > qrow) p[h * 4 + r] = -1e30f;
    }
    float pm = p[0];
#pragma unroll
    for (int i = 1; i < 16; ++i) pm = fmaxf(pm, p[i]);
    pm = fmaxf(pm, __shfl_xor(pm, 16, 64));
    pm = fmaxf(pm, __shfl_xor(pm, 32, 64));
    const float mn = fmaxf(mrow, pm);
    const float scl = __expf(mrow - mn);
    mrow = mn;
    float rs = 0.f;
#pragma unroll
    for (int i = 0; i < 16; ++i) {
      p[i] = __expf(p[i] - mn);
      rs += p[i];
    }
    rs += __shfl_xor(rs, 16, 64);
    rs += __shfl_xor(rs, 32, 64);
    lrow = lrow * scl + rs;
    float sj[4];
#pragma unroll
    for (int j = 0; j < 4; ++j) sj[j] = __shfl(scl, lg * 4 + j, 64);
#pragma unroll
    for (int f = 0; f < 8; ++f)
#pragma unroll
      for (int j = 0; j < 4; ++j) oacc[f][j] *= sj[j];
#pragma unroll
    for (int h = 0; h < 4; ++h)
#pragma unroll
      for (int r = 0; r < 4; ++r)
        Ps[w][lr * PST + h * 16 + lg * 4 + r] = f2bf(p[h * 4 + r]);
    bf16x8 pf0 = *(const bf16x8*)&Ps[w][lr * PST + lg * 8];
    bf16x8 pf1 = *(const bf16x8*)&Ps[w][lr * PST + 32 + lg * 8];
    __builtin_amdgcn_s_setprio(1);
#pragma unroll
    for (int f = 0; f < 8; ++f) {
      bf16x8 vf0 = *(const bf16x8*)&Vt[cur][(size_t)(f * 16 + lr) * VST + lg * 8];
      bf16x8 vf1 = *(const bf16x8*)&Vt[cur][(size_t)(f * 16 + lr) * VST + 32 + lg * 8];
      oacc[f] = mfma16(pf0, vf0, oacc[f]);
      oacc[f] = mfma16(pf1, vf1, oacc[f]);
    }
    __builtin_amdgcn_s_setprio(0);
    __builtin_amdgcn_sched_barrier(0);
    __builtin_amdgcn_s_barrier();
    __builtin_amdgcn_sched_barrier(0);
  }

  const float inv = 1.0f / lrow;
  float ij[4];
#pragma unroll
  for (int j = 0; j < 4; ++j) ij[j] = __shfl(inv, lg * 4 + j, 64);
  u16* Op = O + base_out;
#pragma unroll
  for (int f = 0; f < 8; ++f)
#pragma unroll
    for (int j = 0; j < 4; ++j)
      Op[(size_t)(q0 + w * 16 + lg * 4 + j) * ld_out + f * 16 + lr] =
          f2bf(oacc[f][j] * ij[j]);
}

// merged joint-pair attention: block processes q-tiles A=64*(31-pr) and
// B=64*pr against ONE K/V staging sweep (B's KV range is a prefix of A's:
// compute B only while tt <= pr). Staging -26% vs twin-call. Defer-max (T13)
// skips the oacc rescale when the running max doesn't grow by >8.
// O aliases Q (disjoint row regions per block).
#define TILE_COMPUTE(QT, QROW, QF, MROW, LROW, OACC)                           \
  {                                                                            \
    float p[16];                                                               \
    __builtin_amdgcn_s_setprio(1);                                             \
    _Pragma("unroll") for (int h = 0; h < 4; ++h) {                            \
      f32x4 s = {0.f, 0.f, 0.f, 0.f};                                          \
      _Pragma("unroll") for (int ds = 0; ds < 4; ++ds) {                       \
        const int ch = (ds * 4 + lg) ^ (lr & 7);                               \
        bf16x8 kf = *(const bf16x8*)(Ks[cur] +                                 \
                                     (size_t)(h * 16 + lr) * HD_ + ch * 8);    \
        s = mfma16(kf, QF[ds], s);                                             \
      }                                                                        \
      _Pragma("unroll") for (int r = 0; r < 4; ++r) p[h * 4 + r] = s[r] * sc;  \
    }                                                                          \
    __builtin_amdgcn_s_setprio(0);                                             \
    if (kv0 + KB - 1 > (QT) + w * 16) {                                        \
      _Pragma("unroll") for (int h = 0; h < 4; ++h)                            \
          _Pragma("unroll") for (int r = 0; r < 4; ++r) if (kv0 + h * 16 +     \
                                                            lg * 4 + r >      \
                                                            (QROW))           \
              p[h * 4 + r] = -1e30f;                                           \
    }                                                                          \
    float pm = p[0];                                                           \
    _Pragma("unroll") for (int i = 1; i < 16; ++i) pm = fmaxf(pm, p[i]);       \
    pm = fmaxf(pm, __shfl_xor(pm, 16, 64));                                    \
    pm = fmaxf(pm, __shfl_xor(pm, 32, 64));                                    \
    if (!__all(pm <= (MROW) + 8.f)) {                                          \
      const float mn = fmaxf(MROW, pm);                                        \
      const float scl = __expf((MROW)-mn);                                     \
      MROW = mn;                                                               \
      float sj[4];                                                             \
      _Pragma("unroll") for (int j = 0; j < 4; ++j) sj[j] =                    \
          __shfl(scl, lg * 4 + j, 64);                                         \
      _Pragma("unroll") for (int f = 0; f < 8; ++f)                            \
          _Pragma("unroll") for (int j = 0; j < 4; ++j) OACC[f][j] *= sj[j];   \
      LROW *= scl;                                                             \
    }                                                                          \
    float rs = 0.f;                                                            \
    _Pragma("unroll") for (int i = 0; i < 16; ++i) {                           \
      p[i] = __expf(p[i] - (MROW));                                            \
      rs += p[i];                                                              \
    }                                                                          \
    rs += __shfl_xor(rs, 16, 64);                                              \
    rs += __shfl_xor(rs, 32, 64);                                              \
    LROW += rs;                                                                \
    _Pragma("unroll") for (int h = 0; h < 4; ++h)                              \
        _Pragma("unroll") for (int r = 0; r < 4; ++r)                          \
            Ps[w][lr * PST + h * 16 + lg * 4 + r] = f2bf(p[h * 4 + r]);        \
    bf16x8 pf0 = *(const bf16x8*)&Ps[w][lr * PST + lg * 8];                    \
    bf16x8 pf1 = *(const bf16x8*)&Ps[w][lr * PST + 32 + lg * 8];               \
    __builtin_amdgcn_s_setprio(1);                                             \
    _Pragma("unroll") for (int f = 0; f < 8; ++f) {                            \
      bf16x8 vf0 =                                                             \
          *(const bf16x8*)&Vt[cur][(size_t)(f * 16 + lr) * VST + lg * 8];      \
      bf16x8 vf1 =                                                             \
          *(const bf16x8*)&Vt[cur][(size_t)(f * 16 + lr) * VST + 32 + lg * 8]; \
      OACC[f] = mfma16(pf0, vf0, OACC[f]);                                     \
      OACC[f] = mfma16(pf1, vf1, OACC[f]);                                     \
    }                                                                          \
    __builtin_amdgcn_s_setprio(0);                                             \
  }

__global__ __launch_bounds__(256) void k_attn_full(const u16* Q, const u16* Kd,
                                                   const u16* V, u16* O) {
  const int lin = blockIdx.y * gridDim.x + blockIdx.x;  // grid (16,32) = 512
  const int work = (lin & 7) * 64 + (lin >> 3);         // bijective XCD chunk
  const int bh = work >> 4;
  const int pr = work & 15;
  const int b = bh >> 4, h = bh & 15;
  const size_t base = ((size_t)b * S_) * D_ + (size_t)h * HD_;
  const int qA = 64 * (31 - pr), qB = 64 * pr;

  const int t = threadIdx.x, w = t >> 6, l = t & 63, lr = l & 15, lg = l >> 4;

  __shared__ u16 Ks[2][KB * HD_];
  __shared__ u16 Vt[2][HD_ * VST];
  __shared__ u16 Ps[4][16 * PST];

  bf16x8 qfA[4], qfB[4];
  {
    const u16* qp = Q + base + (size_t)(qA + w * 16 + lr) * D_;
#pragma unroll
    for (int ds = 0; ds < 4; ++ds)
      qfA[ds] = *(const bf16x8*)(qp + ds * 32 + lg * 8);
    qp = Q + base + (size_t)(qB + w * 16 + lr) * D_;
#pragma unroll
    for (int ds = 0; ds < 4; ++ds)
      qfB[ds] = *(const bf16x8*)(qp + ds * 32 + lg * 8);
  }

  f32x4 oaccA[8], oaccB[8];
#pragma unroll
  for (int f = 0; f < 8; ++f) {
    oaccA[f] = f32x4{0.f, 0.f, 0.f, 0.f};
    oaccB[f] = f32x4{0.f, 0.f, 0.f, 0.f};
  }
  float mrowA = -1e30f, lrowA = 0.f, mrowB = -1e30f, lrowB = 0.f;
  const int qrowA = qA + w * 16 + lr, qrowB = qB + w * 16 + lr;
  const int ntA = qA / KB + 1;  // 32 - pr
  const float sc = 0.08838834764831845f;

  const int c1 = t + 256;
  const int kk20 = (t & 31) * 2, d00 = (t >> 5) * 8;
  const int kk21 = (c1 & 31) * 2, d01 = (c1 >> 5) * 8;

  bf16x8 vc[4];

  // prologue: stage tile 0
#pragma unroll
  for (int r = 0; r < 4; ++r) {
    const int c = t + 256 * r;
    const int row = c >> 4, c16 = c & 15;
    const int gc = c16 ^ (row & 7);
    gload16(Kd + base + (size_t)row * D_ + gc * 8,
            (char*)Ks[0] + (size_t)(w + 4 * r) * 1024);
  }
  vc[0] = *(const bf16x8*)(V + base + (size_t)kk20 * D_ + d00);
  vc[1] = *(const bf16x8*)(V + base + (size_t)(kk20 + 1) * D_ + d00);
  vc[2] = *(const bf16x8*)(V + base + (size_t)kk21 * D_ + d01);
  vc[3] = *(const bf16x8*)(V + base + (size_t)(kk21 + 1) * D_ + d01);

  for (int tt = 0; tt < ntA; ++tt) {
    const int cur = tt & 1;
    const int kv0 = tt * KB;
    const bool more = (tt + 1 < ntA);

    if (more) {
      const int kvn = kv0 + KB;
#pragma unroll
      for (int r = 0; r < 4; ++r) {
        const int c = t + 256 * r;
        const int row = c >> 4, c16 = c & 15;
        const int gc = c16 ^ (row & 7);
        gload16(Kd + base + (size_t)(kvn + row) * D_ + gc * 8,
                (char*)Ks[cur ^ 1] + (size_t)(w + 4 * r) * 1024);
      }
      asm volatile("s_waitcnt vmcnt(4)" ::: "memory");
    } else {
      asm volatile("s_waitcnt vmcnt(0)" ::: "memory");
    }
    __builtin_amdgcn_sched_barrier(0);

    {
      u16* vt = Vt[cur];
#pragma unroll
      for (int j = 0; j < 8; ++j) {
        unsigned p0 = (unsigned)(unsigned short)vc[0][j] |
                      ((unsigned)(unsigned short)vc[1][j] << 16);
        *(unsigned*)&vt[(size_t)(d00 + j) * VST + kk20] = p0;
        unsigned p1 = (unsigned)(unsigned short)vc[2][j] |
                      ((unsigned)(unsigned short)vc[3][j] << 16);
        *(unsigned*)&vt[(size_t)(d01 + j) * VST + kk21] = p1;
      }
    }
    if (more) {
      const int kvn = kv0 + KB;
      vc[0] = *(const bf16x8*)(V + base + (size_t)(kvn + kk20) * D_ + d00);
      vc[1] = *(const bf16x8*)(V + base + (size_t)(kvn + kk20 + 1) * D_ + d00);
      vc[2] = *(const bf16x8*)(V + base + (size_t)(kvn + kk21) * D_ + d01);
      vc[3] = *(const bf16x8*)(V + base + (size_t)(kvn + kk21 + 1) * D_ + d01);
    }
    asm volatile("s_waitcnt lgkmcnt(0)" ::: "memory");
    __builtin_amdgcn_sched_barrier(0);
    __builtin_amdgcn_s_barrier();
    __builtin_amdgcn_sched_barrier(0);

    TILE_COMPUTE(qA, qrowA, qfA, mrowA, lrowA, oaccA);
    if (tt <= pr) {
      TILE_COMPUTE(qB, qrowB, qfB, mrowB, lrowB, oaccB);
    }

    __builtin_amdgcn_sched_barrier(0);
    __builtin_amdgcn_s_barrier();
    __builtin_amdgcn_sched_barrier(0);
  }

  {
    const float inv = 1.0f / lrowA;
    float ij[4];
#pragma unroll
    for (int j = 0; j < 4; ++j) ij[j] = __shfl(inv, lg * 4 + j, 64);
    u16* Op = O + base;
#pragma unroll
    for (int f = 0; f < 8; ++f)
#pragma unroll
      for (int j = 0; j < 4; ++j)
        Op[(size_t)(qA + w * 16 + lg * 4 + j) * D_ + f * 16 + lr] =
            f2bf(oaccA[f][j] * ij[j]);
  }
  {
    const float inv = 1.0f / lrowB;
    float ij[4];
#pragma unroll
    for (int j = 0; j < 4; ++j) ij[j] = __shfl(inv, lg * 4 + j, 64);
    u16* Op = O + base;
#pragma unroll
    for (int f = 0; f < 8; ++f)
#pragma unroll
      for (int j = 0; j < 4; ++j)
        Op[(size_t)(qB + w * 16 + lg * 4 + j) * D_ + f * 16 + lr] =
            f2bf(oaccB[f][j] * ij[j]);
  }
}
#undef TILE_COMPUTE

// grouped fallback
__global__ __launch_bounds__(256) void k_attn_g(const u16* __restrict__ Q,
                                                const u16* __restrict__ Kd,
                                                const u16* __restrict__ V,
                                                u16* __restrict__ O, int g) {
  const int by = blockIdx.y;
  const int b = by >> 2, hh = by & 3;
  const size_t base_in = ((size_t)b * S_) * GW + (size_t)hh * HD_;
  const size_t base_out = ((size_t)b * S_) * D_ + (size_t)(g * 4 + hh) * HD_;
  attn_body(Q, Kd, V, O, base_in, base_out, GW, D_, blockIdx.x * 64);
}

extern "C" void kernel_launch(void* const* d_in, const int* in_sizes, int n_in,
                              void* d_out, int out_size, void* d_ws,
                              size_t ws_size, hipStream_t stream) {
  (void)in_sizes; (void)n_in; (void)out_size;
  const float* x = (const float*)d_in[0];
  const float* wq = (const float*)d_in[1];
  const float* bq = (const float*)d_in[2];
  const float* wk = (const float*)d_in[3];
  const float* bk = (const float*)d_in[4];
  const float* wv = (const float*)d_in[5];
  const float* bv = (const float*)d_in[6];
  const float* wo = (const float*)d_in[7];
  const float* bo = (const float*)d_in[8];
  float* out = (float*)d_out;

  const size_t XB = (size_t)B_ * S_ * D_ * 2;  // 16,777,216
  const size_t WB3 = 3 * (size_t)D_ * D_ * 2;  // 25,165,824
  const size_t WB1 = (size_t)D_ * D_ * 2;      // 8,388,608
  const size_t TB = (size_t)S_ * 64 * 8;       // 1,048,576 rope table
  char* ws = (char*)d_ws;
  char* ob = (char*)d_out;

  u16 *xb, *q, *k, *v, *wqkvb = nullptr, *wob = nullptr;
  float2* tab = nullptr;
  int tier;
  if (ws_size >= 4 * XB + WB3 + WB1 + TB) {
    xb = (u16*)ws; q = (u16*)(ws + XB); k = (u16*)(ws + 2 * XB);
    v = (u16*)(ws + 3 * XB);
    wqkvb = (u16*)(ws + 4 * XB); wob = (u16*)(ws + 4 * XB + WB3);
    tab = (float2*)(ws + 4 * XB + WB3 + WB1);
    tier = 1;
  } else if (ws_size >= 3 * XB + WB3 + WB1 + TB) {
    xb = (u16*)ob;
    q = (u16*)ws; k = (u16*)(ws + XB); v = (u16*)(ws + 2 * XB);
    wqkvb = (u16*)(ws + 3 * XB); wob = (u16*)(ws + 3 * XB + WB3);
    tab = (float2*)(ws + 3 * XB + WB3 + WB1);
    tier = 1;
  } else if (ws_size >= 2 * XB + WB3 + TB) {
    xb = (u16*)ob; v = (u16*)(ob + XB);
    q = (u16*)ws; k = (u16*)(ws + XB);
    wqkvb = (u16*)(ws + 2 * XB);
    tab = (float2*)(ws + 2 * XB + WB3);
    tier = 2;
  } else if (ws_size >= 2 * XB) {
    xb = (u16*)ob; v = (u16*)(ob + XB);
    q = (u16*)ws; k = (u16*)(ws + XB);
    tier = 3;
  } else {
    tier = 4;
  }

  if (tier == 1 || tier == 2) {
    dim3 gc(4096, 6);
    k_cvt_all<<<gc, 256, 0, stream>>>(x, wq, wk, wv, wo, xb, wqkvb, wob, tab);
    dim3 g1(16, 32, 3);
    k_gemm_qkv_bb<<<g1, 256, 0, stream>>>(xb, wqkvb, bq, bk, bv, q, k, v, tab);
    dim3 g2(16, 32);
    k_attn_full<<<g2, 256, 0, stream>>>(q, k, v, q);
    dim3 g3(16, 32);
    if (tier == 1)
      k_gemm_out_bb<<<g3, 256, 0, stream>>>(q, wob, bo, out);
    else
      k_gemm_out<<<g3, 256, 0, stream>>>(q, wo, bo, out);
  } else if (tier == 3) {
    dim3 gc(4096, 1);
    k_cvt_all<<<gc, 256, 0, stream>>>(x, wq, wk, wv, wo, xb, xb, nullptr, nullptr);
    dim3 g1(16, 32, 3);
    k_gemm_qkv_xb<<<g1, 256, 0, stream>>>(xb, wq, bq, wk, bk, wv, bv, q, k, v);
    k_rope_full<<<16384, 256, 0, stream>>>(q, k);
    dim3 g2(16, 32);
    k_attn_full<<<g2, 256, 0, stream>>>(q, k, v, q);
    dim3 g3(16, 32);
    k_gemm_out<<<g3, 256, 0, stream>>>(q, wo, bo, out);
  } else {
    u16* qg = (u16*)ob;
    u16* kg = qg + (size_t)(B_ * S_) * GW;
    u16* vg = kg + (size_t)(B_ * S_) * GW;
    u16* ao = (u16*)ws;
    for (int g = 0; g < 4; ++g) {
      dim3 g1(4, 32, 3);
      k_gemm_qkv_g<<<g1, 256, 0, stream>>>(x, wq, bq, wk, bk, wv, bv, qg, kg, vg, g);
      k_rope_g<<<4096, 256, 0, stream>>>(qg, kg);
      dim3 g2(32, 8);
      k_attn_g<<<g2, 256, 0, stream>>>(qg, kg, vg, ao, g);
    }
    dim3 g3(16, 32);
    k_gemm_out<<<g3, 256, 0, stream>>>(ao, wo, bo, out);
  }
}

// Round 15
// 272.072 us; speedup vs baseline: 1.1838x; 1.0165x over previous
//
#include <hip/hip_runtime.h>

typedef unsigned short u16;
typedef short bf16x8 __attribute__((ext_vector_type(8)));
typedef float f32x4 __attribute__((ext_vector_type(4)));

#define B_ 2
#define S_ 2048
#define D_ 2048
#define HD_ 128
#define GW 512   // head-group width for fallback path
#define KB 64    // attention KV tile rows
#define VST 72   // Vt row stride (u16)
#define PST 72   // Ps row stride (u16)

__device__ __forceinline__ float bf2f(u16 h) {
  unsigned u = ((unsigned)h) << 16;
  return __builtin_bit_cast(float, u);
}
__device__ __forceinline__ u16 f2bf(float f) {
  unsigned u = __builtin_bit_cast(unsigned, f);
  u += 0x7FFF + ((u >> 16) & 1);
  return (u16)(u >> 16);
}
__device__ __forceinline__ bf16x8 cvt8(const float* p) {
  float4 a = *(const float4*)p;
  float4 b = *(const float4*)(p + 4);
  bf16x8 r;
  r[0] = (short)f2bf(a.x); r[1] = (short)f2bf(a.y);
  r[2] = (short)f2bf(a.z); r[3] = (short)f2bf(a.w);
  r[4] = (short)f2bf(b.x); r[5] = (short)f2bf(b.y);
  r[6] = (short)f2bf(b.z); r[7] = (short)f2bf(b.w);
  return r;
}

__device__ __forceinline__ void gload16(const void* g, void* lds) {
  __builtin_amdgcn_global_load_lds(
      (const __attribute__((address_space(1))) unsigned*)g,
      (__attribute__((address_space(3))) unsigned*)lds, 16, 0, 0);
}

__device__ __forceinline__ f32x4 mfma16(bf16x8 a, bf16x8 b, f32x4 c) {
  return __builtin_amdgcn_mfma_f32_16x16x32_bf16(a, b, c, 0, 0, 0);
}

// ---------------- flat f32->bf16 convert + RoPE table (no dead blocks).
// ranges: [0,4096) x; [4096,6144) wq; [6144,8192) wk; [8192,10240) wv;
// [10240,12288) wo (skip if wob null); [12288,12800) tab (skip if null).
__global__ void k_cvt_all(const float* __restrict__ x, const float* __restrict__ wq,
                          const float* __restrict__ wk, const float* __restrict__ wv,
                          const float* __restrict__ wo, u16* __restrict__ xb,
                          u16* __restrict__ wqkvb, u16* wob, float2* tab) {
  const int bx = blockIdx.x;
  if (bx >= 12288) {
    if (tab != nullptr) {
      const int i = (bx - 12288) * 256 + threadIdx.x;  // < 131072 = 2048*64
      const int s = i >> 6, ip = i & 63;
      const float freq = expf(-(float)ip * 0.14391157f);  // ln(10000)/64
      float sv, cv;
      sincosf((float)s * freq, &sv, &cv);
      tab[i] = make_float2(cv, sv);
    }
    return;
  }
  const float* src;
  u16* dst;
  int i;
  if (bx < 4096) { src = x; dst = xb; i = bx * 256 + threadIdx.x; }
  else if (bx < 6144) { src = wq; dst = wqkvb; i = (bx - 4096) * 256 + threadIdx.x; }
  else if (bx < 8192) { src = wk; dst = wqkvb + 4194304; i = (bx - 6144) * 256 + threadIdx.x; }
  else if (bx < 10240) { src = wv; dst = wqkvb + 8388608; i = (bx - 8192) * 256 + threadIdx.x; }
  else {
    if (wob == nullptr) return;
    src = wo; dst = wob; i = (bx - 10240) * 256 + threadIdx.x;
  }
  *(bf16x8*)(dst + (size_t)i * 8) = cvt8(src + (size_t)i * 8);
}

// XCD-bijective remap for 512-block GEMM grids (m204 form): each XCD gets a
// contiguous 64-work chunk = 4 m-tiles x 16 n-tiles (A-panels 2MB, L2-fits);
// same residue across z-slices -> A shared across Q/K/V on the same XCD.
__device__ __forceinline__ void xcd_remap512(int& m0, int& n0) {
  const int lin = blockIdx.y * 16 + blockIdx.x;
  const int wk = (lin & 7) * 64 + (lin >> 3);
  m0 = (wk >> 4) * 128;
  n0 = (wk & 15) * 128;
}

// ---------------- m97-structure GEMM (proven 138us for QKV w/ fused rope).
// AM/WM: 1 = bf16 via global_load_lds, 0 = f32 reg-stage+cvt. CM: 0 bf16/1 f32.
// tab != nullptr (CM=0 only): apply interleaved RoPE in epilogue.
template <int AM, int WM, int CM>
__device__ __forceinline__ void gemm_body(const void* Ap, const void* Wp,
                                          const float* __restrict__ bias,
                                          void* Cp, int ldc,
                                          const float2* __restrict__ tab,
                                          int m0, int n0) {
  constexpr int K = 2048;
  __shared__ u16 As[128 * 32];
  __shared__ u16 Bs[128 * 32];
  const int t = threadIdx.x;
  const int w = t >> 6, l = t & 63, lr = l & 15, lg = l >> 4;
  const int wr = w >> 1, wc = w & 1;

  f32x4 acc[4][4];
#pragma unroll
  for (int i = 0; i < 4; ++i)
#pragma unroll
    for (int j = 0; j < 4; ++j) acc[i][j] = f32x4{0.f, 0.f, 0.f, 0.f};

  const int rowA0 = t >> 2, ko0 = (t & 3) * 8;
  const int rowA1 = (t + 256) >> 2, ko1 = ((t + 256) & 3) * 8;

  for (int kt = 0; kt < K; kt += 32) {
    if constexpr (AM == 1) {
      const u16* A = (const u16*)Ap;
      gload16(A + (size_t)(m0 + rowA0) * K + kt + ko0, (char*)As + (size_t)w * 1024);
      gload16(A + (size_t)(m0 + rowA1) * K + kt + ko1, (char*)As + (size_t)(w + 4) * 1024);
    } else {
      const float* A = (const float*)Ap;
      *(bf16x8*)((char*)As + (size_t)t * 16) = cvt8(A + (size_t)(m0 + rowA0) * K + kt + ko0);
      *(bf16x8*)((char*)As + (size_t)(t + 256) * 16) = cvt8(A + (size_t)(m0 + rowA1) * K + kt + ko1);
    }
    if constexpr (WM == 1) {
      const u16* W = (const u16*)Wp;
      gload16(W + (size_t)(n0 + rowA0) * K + kt + ko0, (char*)Bs + (size_t)w * 1024);
      gload16(W + (size_t)(n0 + rowA1) * K + kt + ko1, (char*)Bs + (size_t)(w + 4) * 1024);
    } else {
      const float* W = (const float*)Wp;
      *(bf16x8*)((char*)Bs + (size_t)t * 16) = cvt8(W + (size_t)(n0 + rowA0) * K + kt + ko0);
      *(bf16x8*)((char*)Bs + (size_t)(t + 256) * 16) = cvt8(W + (size_t)(n0 + rowA1) * K + kt + ko1);
    }
    __syncthreads();

    bf16x8 af[4], bw[4];
#pragma unroll
    for (int i = 0; i < 4; ++i) {
      af[i] = *(const bf16x8*)(As + (size_t)(wr * 64 + i * 16 + lr) * 32 + lg * 8);
      bw[i] = *(const bf16x8*)(Bs + (size_t)(wc * 64 + i * 16 + lr) * 32 + lg * 8);
    }
#pragma unroll
    for (int i = 0; i < 4; ++i)
#pragma unroll
      for (int j = 0; j < 4; ++j)
        acc[i][j] = mfma16(af[i], bw[j], acc[i][j]);
    __syncthreads();
  }

#pragma unroll
  for (int i = 0; i < 4; ++i) {
#pragma unroll
    for (int j = 0; j < 4; ++j) {
      const int col = n0 + wc * 64 + j * 16 + lr;
      const float bv = bias[col];
      const int row = m0 + wr * 64 + i * 16 + lg * 4;
      if (CM == 0 && tab != nullptr) {
        const int ip = (col & 127) >> 1;
        const int odd = col & 1;
#pragma unroll
        for (int r = 0; r < 4; ++r) {
          const float v = acc[i][j][r] + bv;
          const float p = __shfl_xor(v, 1, 64);
          const float2 cs = tab[((row + r) & (S_ - 1)) * 64 + ip];
          const float o = odd ? (p * cs.y + v * cs.x) : (v * cs.x - p * cs.y);
          ((u16*)Cp)[(size_t)(row + r) * ldc + col] = f2bf(o);
        }
      } else {
#pragma unroll
        for (int r = 0; r < 4; ++r) {
          if constexpr (CM == 1)
            ((float*)Cp)[(size_t)(row + r) * ldc + col] = acc[i][j][r] + bv;
          else
            ((u16*)Cp)[(size_t)(row + r) * ldc + col] = f2bf(acc[i][j][r] + bv);
        }
      }
    }
  }
}

__global__ __launch_bounds__(256) void k_gemm_qkv_bb(
    const u16* __restrict__ xb, const u16* __restrict__ wqkvb,
    const float* __restrict__ bq, const float* __restrict__ bk,
    const float* __restrict__ bv, u16* __restrict__ q, u16* __restrict__ k,
    u16* __restrict__ v, const float2* __restrict__ tab) {
  const int z = blockIdx.z;
  const u16* W = wqkvb + (size_t)z * D_ * D_;
  const float* bias = z == 0 ? bq : (z == 1 ? bk : bv);
  u16* C = z == 0 ? q : (z == 1 ? k : v);
  int m0, n0;
  xcd_remap512(m0, n0);
  gemm_body<1, 1, 0>(xb, W, bias, C, D_, z == 2 ? nullptr : tab, m0, n0);
}

__global__ __launch_bounds__(256) void k_gemm_out_bb(
    const u16* __restrict__ ao, const u16* __restrict__ wob,
    const float* __restrict__ bo, float* __restrict__ out) {
  int m0, n0;
  xcd_remap512(m0, n0);
  gemm_body<1, 1, 1>(ao, wob, bo, out, D_, nullptr, m0, n0);
}

__global__ __launch_bounds__(256) void k_gemm_qkv_xb(
    const u16* __restrict__ xb, const float* __restrict__ wq,
    const float* __restrict__ bq, const float* __restrict__ wk,
    const float* __restrict__ bk, const float* __restrict__ wv,
    const float* __restrict__ bv, u16* __restrict__ q, u16* __restrict__ k,
    u16* __restrict__ v) {
  const int z = blockIdx.z;
  const float* W = z == 0 ? wq : (z == 1 ? wk : wv);
  const float* bias = z == 0 ? bq : (z == 1 ? bk : bv);
  u16* C = z == 0 ? q : (z == 1 ? k : v);
  int m0, n0;
  xcd_remap512(m0, n0);
  gemm_body<1, 0, 0>(xb, W, bias, C, D_, nullptr, m0, n0);
}

__global__ __launch_bounds__(256) void k_gemm_out(const u16* __restrict__ ao,
                                                  const float* __restrict__ wo,
                                                  const float* __restrict__ bo,
                                                  float* __restrict__ out) {
  int m0, n0;
  xcd_remap512(m0, n0);
  gemm_body<1, 0, 1>(ao, wo, bo, out, D_, nullptr, m0, n0);
}

__global__ __launch_bounds__(256) void k_gemm_qkv_g(
    const float* __restrict__ x, const float* __restrict__ wq,
    const float* __restrict__ bq, const float* __restrict__ wk,
    const float* __restrict__ bk, const float* __restrict__ wv,
    const float* __restrict__ bv, u16* __restrict__ qg, u16* __restrict__ kg,
    u16* __restrict__ vg, int g) {
  const int z = blockIdx.z;
  const float* W = (z == 0 ? wq : (z == 1 ? wk : wv)) + (size_t)g * GW * D_;
  const float* bias = (z == 0 ? bq : (z == 1 ? bk : bv)) + g * GW;
  u16* C = z == 0 ? qg : (z == 1 ? kg : vg);
  gemm_body<0, 0, 0>(x, W, bias, C, GW, nullptr, blockIdx.y * 128,
                     blockIdx.x * 128);
}

// ---------------- RoPE (interleaved) in place, for tiers without table space
__device__ __forceinline__ void rope_one(u16* p, float cv, float sv) {
  unsigned u = *(const unsigned*)p;
  float x1 = bf2f((u16)(u & 0xffff)), x2 = bf2f((u16)(u >> 16));
  unsigned r = (unsigned)f2bf(x1 * cv - x2 * sv) |
               ((unsigned)f2bf(x1 * sv + x2 * cv) << 16);
  *(unsigned*)p = r;
}

__global__ void k_rope_full(u16* q, u16* kk) {
  const int idx = blockIdx.x * 256 + threadIdx.x;
  const int i = idx & 63;
  const int hh = (idx >> 6) & 15;
  const int bs = idx >> 10;
  const int s = bs & (S_ - 1);
  const float freq = expf(-(float)i * 0.14391157f);
  float sv, cv;
  sincosf((float)s * freq, &sv, &cv);
  const size_t off = (size_t)bs * D_ + (size_t)hh * HD_ + 2 * i;
  rope_one(q + off, cv, sv);
  rope_one(kk + off, cv, sv);
}

__global__ void k_rope_g(u16* q, u16* kk) {
  const int idx = blockIdx.x * 256 + threadIdx.x;
  const int i = idx & 63;
  const int hh = (idx >> 6) & 3;
  const int bs = idx >> 8;
  const int s = bs & (S_ - 1);
  const float freq = expf(-(float)i * 0.14391157f);
  float sv, cv;
  sincosf((float)s * freq, &sv, &cv);
  const size_t off = (size_t)bs * GW + (size_t)hh * HD_ + 2 * i;
  rope_one(q + off, cv, sv);
  rope_one(kk + off, cv, sv);
}

// ---------------- Flash attention (causal), swapped-QK^T, double-buffered.
// attn_body: single-q-tile version (kept for grouped fallback).
__device__ __forceinline__ void attn_body(const u16* Q, const u16* Kd,
                                          const u16* V, u16* O,
                                          size_t base_in, size_t base_out,
                                          int ld_in, int ld_out, int q0) {
  const int t = threadIdx.x, w = t >> 6, l = t & 63, lr = l & 15, lg = l >> 4;

  __shared__ u16 Ks[2][KB * HD_];
  __shared__ u16 Vt[2][HD_ * VST];
  __shared__ u16 Ps[4][16 * PST];

  bf16x8 qf[4];
  {
    const u16* qp = Q + base_in + (size_t)(q0 + w * 16 + lr) * ld_in;
#pragma unroll
    for (int ds = 0; ds < 4; ++ds)
      qf[ds] = *(const bf16x8*)(qp + ds * 32 + lg * 8);
  }

  f32x4 oacc[8];
#pragma unroll
  for (int f = 0; f < 8; ++f) oacc[f] = f32x4{0.f, 0.f, 0.f, 0.f};
  float mrow = -1e30f, lrow = 0.f;

  const int qrow = q0 + w * 16 + lr;
  const int nt = q0 / KB + 1;
  const float sc = 0.08838834764831845f;

  const int c1 = t + 256;
  const int kk20 = (t & 31) * 2, d00 = (t >> 5) * 8;
  const int kk21 = (c1 & 31) * 2, d01 = (c1 >> 5) * 8;

  bf16x8 vc[4];

#pragma unroll
  for (int r = 0; r < 4; ++r) {
    const int c = t + 256 * r;
    const int row = c >> 4, c16 = c & 15;
    const int gc = c16 ^ (row & 7);
    gload16(Kd + base_in + (size_t)row * ld_in + gc * 8,
            (char*)Ks[0] + (size_t)(w + 4 * r) * 1024);
  }
  vc[0] = *(const bf16x8*)(V + base_in + (size_t)kk20 * ld_in + d00);
  vc[1] = *(const bf16x8*)(V + base_in + (size_t)(kk20 + 1) * ld_in + d00);
  vc[2] = *(const bf16x8*)(V + base_in + (size_t)kk21 * ld_in + d01);
  vc[3] = *(const bf16x8*)(V + base_in + (size_t)(kk21 + 1) * ld_in + d01);

  for (int tt = 0; tt < nt; ++tt) {
    const int cur = tt & 1;
    const int kv0 = tt * KB;
    const bool more = (tt + 1 < nt);

    if (more) {
      const int kvn = kv0 + KB;
#pragma unroll
      for (int r = 0; r < 4; ++r) {
        const int c = t + 256 * r;
        const int row = c >> 4, c16 = c & 15;
        const int gc = c16 ^ (row & 7);
        gload16(Kd + base_in + (size_t)(kvn + row) * ld_in + gc * 8,
                (char*)Ks[cur ^ 1] + (size_t)(w + 4 * r) * 1024);
      }
      asm volatile("s_waitcnt vmcnt(4)" ::: "memory");
    } else {
      asm volatile("s_waitcnt vmcnt(0)" ::: "memory");
    }
    __builtin_amdgcn_sched_barrier(0);

    {
      u16* vt = Vt[cur];
#pragma unroll
      for (int j = 0; j < 8; ++j) {
        unsigned p0 = (unsigned)(unsigned short)vc[0][j] |
                      ((unsigned)(unsigned short)vc[1][j] << 16);
        *(unsigned*)&vt[(size_t)(d00 + j) * VST + kk20] = p0;
        unsigned p1 = (unsigned)(unsigned short)vc[2][j] |
                      ((unsigned)(unsigned short)vc[3][j] << 16);
        *(unsigned*)&vt[(size_t)(d01 + j) * VST + kk21] = p1;
      }
    }
    if (more) {
      const int kvn = kv0 + KB;
      vc[0] = *(const bf16x8*)(V + base_in + (size_t)(kvn + kk20) * ld_in + d00);
      vc[1] = *(const bf16x8*)(V + base_in + (size_t)(kvn + kk20 + 1) * ld_in + d00);
      vc[2] = *(const bf16x8*)(V + base_in + (size_t)(kvn + kk21) * ld_in + d01);
      vc[3] = *(const bf16x8*)(V + base_in + (size_t)(kvn + kk21 + 1) * ld_in + d01);
    }
    asm volatile("s_waitcnt lgkmcnt(0)" ::: "memory");
    __builtin_amdgcn_sched_barrier(0);
    __builtin_amdgcn_s_barrier();
    __builtin_amdgcn_sched_barrier(0);

    float p[16];
    __builtin_amdgcn_s_setprio(1);
#pragma unroll
    for (int h = 0; h < 4; ++h) {
      f32x4 s = {0.f, 0.f, 0.f, 0.f};
#pragma unroll
      for (int ds = 0; ds < 4; ++ds) {
        const int ch = (ds * 4 + lg) ^ (lr & 7);
        bf16x8 kf = *(const bf16x8*)(Ks[cur] + (size_t)(h * 16 + lr) * HD_ + ch * 8);
        s = mfma16(kf, qf[ds], s);
      }
#pragma unroll
      for (int r = 0; r < 4; ++r) p[h * 4 + r] = s[r] * sc;
    }
    __builtin_amdgcn_s_setprio(0);
    if (kv0 + KB - 1 > q0 + w * 16) {
#pragma unroll
      for (int h = 0; h < 4; ++h)
#pragma unroll
        for (int r = 0; r < 4; ++r)
          if (kv0 + h * 16 + lg * 4 + r > qrow) p[h * 4 + r] = -1e30f;
    }
    float pm = p[0];
#pragma unroll
    for (int i = 1; i < 16; ++i) pm = fmaxf(pm, p[i]);
    pm = fmaxf(pm, __shfl_xor(pm, 16, 64));
    pm = fmaxf(pm, __shfl_xor(pm, 32, 64));
    const float mn = fmaxf(mrow, pm);
    const float scl = __expf(mrow - mn);
    mrow = mn;
    float rs = 0.f;
#pragma unroll
    for (int i = 0; i < 16; ++i) {
      p[i] = __expf(p[i] - mn);
      rs += p[i];
    }
    rs += __shfl_xor(rs, 16, 64);
    rs += __shfl_xor(rs, 32, 64);
    lrow = lrow * scl + rs;
    float sj[4];
#pragma unroll
    for (int j = 0; j < 4; ++j) sj[j] = __shfl(scl, lg * 4 + j, 64);
#pragma unroll
    for (int f = 0; f < 8; ++f)
#pragma unroll
      for (int j = 0; j < 4; ++j) oacc[f][j] *= sj[j];
#pragma unroll
    for (int h = 0; h < 4; ++h)
#pragma unroll
      for (int r = 0; r < 4; ++r)
        Ps[w][lr * PST + h * 16 + lg * 4 + r] = f2bf(p[h * 4 + r]);
    bf16x8 pf0 = *(const bf16x8*)&Ps[w][lr * PST + lg * 8];
    bf16x8 pf1 = *(const bf16x8*)&Ps[w][lr * PST + 32 + lg * 8];
    __builtin_amdgcn_s_setprio(1);
#pragma unroll
    for (int f = 0; f < 8; ++f) {
      bf16x8 vf0 = *(const bf16x8*)&Vt[cur][(size_t)(f * 16 + lr) * VST + lg * 8];
      bf16x8 vf1 = *(const bf16x8*)&Vt[cur][(size_t)(f * 16 + lr) * VST + 32 + lg * 8];
      oacc[f] = mfma16(pf0, vf0, oacc[f]);
      oacc[f] = mfma16(pf1, vf1, oacc[f]);
    }
    __builtin_amdgcn_s_setprio(0);
    __builtin_amdgcn_sched_barrier(0);
    __builtin_amdgcn_s_barrier();
    __builtin_amdgcn_sched_barrier(0);
  }

  const float inv = 1.0f / lrow;
  float ij[4];
#pragma unroll
  for (int j = 0; j < 4; ++j) ij[j] = __shfl(inv, lg * 4 + j, 64);
  u16* Op = O + base_out;
#pragma unroll
  for (int f = 0; f < 8; ++f)
#pragma unroll
    for (int j = 0; j < 4; ++j)
      Op[(size_t)(q0 + w * 16 + lg * 4 + j) * ld_out + f * 16 + lr] =
          f2bf(oacc[f][j] * ij[j]);
}

// merged joint-pair attention (R14-verified): q-tiles A=64*(31-pr), B=64*pr
// share ONE K/V staging sweep; defer-max (T13) skips rescale when max growth
// <= 8. O aliases Q (disjoint row regions per block).
#define TILE_COMPUTE(QT, QROW, QF, MROW, LROW, OACC)                           \
  {                                                                            \
    float p[16];                                                               \
    __builtin_amdgcn_s_setprio(1);                                             \
    _Pragma("unroll") for (int h = 0; h < 4; ++h) {                            \
      f32x4 s = {0.f, 0.f, 0.f, 0.f};                                          \
      _Pragma("unroll") for (int ds = 0; ds < 4; ++ds) {                       \
        const int ch = (ds * 4 + lg) ^ (lr & 7);                               \
        bf16x8 kf = *(const bf16x8*)(Ks[cur] +                                 \
                                     (size_t)(h * 16 + lr) * HD_ + ch * 8);    \
        s = mfma16(kf, QF[ds], s);                                             \
      }                                                                        \
      _Pragma("unroll") for (int r = 0; r < 4; ++r) p[h * 4 + r] = s[r] * sc;  \
    }                                                                          \
    __builtin_amdgcn_s_setprio(0);                                             \
    if (kv0 + KB - 1 > (QT) + w * 16) {                                        \
      _Pragma("unroll") for (int h = 0; h < 4; ++h)                            \
          _Pragma("unroll") for (int r = 0; r < 4; ++r) if (kv0 + h * 16 +     \
                                                            lg * 4 + r >      \
                                                            (QROW))           \
              p[h * 4 + r] = -1e30f;                                           \
    }                                                                          \
    float pm = p[0];                                                           \
    _Pragma("unroll") for (int i = 1; i < 16; ++i) pm = fmaxf(pm, p[i]);       \
    pm = fmaxf(pm, __shfl_xor(pm, 16, 64));                                    \
    pm = fmaxf(pm, __shfl_xor(pm, 32, 64));                                    \
    if (!__all(pm <= (MROW) + 8.f)) {                                          \
      const float mn = fmaxf(MROW, pm);                                        \
      const float scl = __expf((MROW)-mn);                                     \
      MROW = mn;                                                               \
      float sj[4];                                                             \
      _Pragma("unroll") for (int j = 0; j < 4; ++j) sj[j] =                    \
          __shfl(scl, lg * 4 + j, 64);                                         \
      _Pragma("unroll") for (int f = 0; f < 8; ++f)                            \
          _Pragma("unroll") for (int j = 0; j < 4; ++j) OACC[f][j] *= sj[j];   \
      LROW *= scl;                                                             \
    }                                                                          \
    float rs = 0.f;                                                            \
    _Pragma("unroll") for (int i = 0; i < 16; ++i) {                           \
      p[i] = __expf(p[i] - (MROW));                                            \
      rs += p[i];                                                              \
    }                                                                          \
    rs += __shfl_xor(rs, 16, 64);                                              \
    rs += __shfl_xor(rs, 32, 64);                                              \
    LROW += rs;                                                                \
    _Pragma("unroll") for (int h = 0; h < 4; ++h)                              \
        _Pragma("unroll") for (int r = 0; r < 4; ++r)                          \
            Ps[w][lr * PST + h * 16 + lg * 4 + r] = f2bf(p[h * 4 + r]);        \
    bf16x8 pf0 = *(const bf16x8*)&Ps[w][lr * PST + lg * 8];                    \
    bf16x8 pf1 = *(const bf16x8*)&Ps[w][lr * PST + 32 + lg * 8];               \
    __builtin_amdgcn_s_setprio(1);                                             \
    _Pragma("unroll") for (int f = 0; f < 8; ++f) {                            \
      bf16x8 vf0 =                                                             \
          *(const bf16x8*)&Vt[cur][(size_t)(f * 16 + lr) * VST + lg * 8];      \
      bf16x8 vf1 =                                                             \
          *(const bf16x8*)&Vt[cur][(size_t)(f * 16 + lr) * VST + 32 + lg * 8]; \
      OACC[f] = mfma16(pf0, vf0, OACC[f]);                                     \
      OACC[f] = mfma16(pf1, vf1, OACC[f]);                                     \
    }                                                                          \
    __builtin_amdgcn_s_setprio(0);                                             \
  }

__global__ __launch_bounds__(256) void k_attn_full(const u16* Q, const u16* Kd,
                                                   const u16* V, u16* O) {
  const int lin = blockIdx.y * gridDim.x + blockIdx.x;  // grid (16,32) = 512
  const int work = (lin & 7) * 64 + (lin >> 3);         // bijective XCD chunk
  const int bh = work >> 4;
  const int pr = work & 15;
  const int b = bh >> 4, h = bh & 15;
  const size_t base = ((size_t)b * S_) * D_ + (size_t)h * HD_;
  const int qA = 64 * (31 - pr), qB = 64 * pr;

  const int t = threadIdx.x, w = t >> 6, l = t & 63, lr = l & 15, lg = l >> 4;

  __shared__ u16 Ks[2][KB * HD_];
  __shared__ u16 Vt[2][HD_ * VST];
  __shared__ u16 Ps[4][16 * PST];

  bf16x8 qfA[4], qfB[4];
  {
    const u16* qp = Q + base + (size_t)(qA + w * 16 + lr) * D_;
#pragma unroll
    for (int ds = 0; ds < 4; ++ds)
      qfA[ds] = *(const bf16x8*)(qp + ds * 32 + lg * 8);
    qp = Q + base + (size_t)(qB + w * 16 + lr) * D_;
#pragma unroll
    for (int ds = 0; ds < 4; ++ds)
      qfB[ds] = *(const bf16x8*)(qp + ds * 32 + lg * 8);
  }

  f32x4 oaccA[8], oaccB[8];
#pragma unroll
  for (int f = 0; f < 8; ++f) {
    oaccA[f] = f32x4{0.f, 0.f, 0.f, 0.f};
    oaccB[f] = f32x4{0.f, 0.f, 0.f, 0.f};
  }
  float mrowA = -1e30f, lrowA = 0.f, mrowB = -1e30f, lrowB = 0.f;
  const int qrowA = qA + w * 16 + lr, qrowB = qB + w * 16 + lr;
  const int ntA = qA / KB + 1;  // 32 - pr
  const float sc = 0.08838834764831845f;

  const int c1 = t + 256;
  const int kk20 = (t & 31) * 2, d00 = (t >> 5) * 8;
  const int kk21 = (c1 & 31) * 2, d01 = (c1 >> 5) * 8;

  bf16x8 vc[4];

  // prologue: stage tile 0
#pragma unroll
  for (int r = 0; r < 4; ++r) {
    const int c = t + 256 * r;
    const int row = c >> 4, c16 = c & 15;
    const int gc = c16 ^ (row & 7);
    gload16(Kd + base + (size_t)row * D_ + gc * 8,
            (char*)Ks[0] + (size_t)(w + 4 * r) * 1024);
  }
  vc[0] = *(const bf16x8*)(V + base + (size_t)kk20 * D_ + d00);
  vc[1] = *(const bf16x8*)(V + base + (size_t)(kk20 + 1) * D_ + d00);
  vc[2] = *(const bf16x8*)(V + base + (size_t)kk21 * D_ + d01);
  vc[3] = *(const bf16x8*)(V + base + (size_t)(kk21 + 1) * D_ + d01);

  for (int tt = 0; tt < ntA; ++tt) {
    const int cur = tt & 1;
    const int kv0 = tt * KB;
    const bool more = (tt + 1 < ntA);

    if (more) {
      const int kvn = kv0 + KB;
#pragma unroll
      for (int r = 0; r < 4; ++r) {
        const int c = t + 256 * r;
        const int row = c >> 4, c16 = c & 15;
        const int gc = c16 ^ (row & 7);
        gload16(Kd + base + (size_t)(kvn + row) * D_ + gc * 8,
                (char*)Ks[cur ^ 1] + (size_t)(w + 4 * r) * 1024);
      }
      asm volatile("s_waitcnt vmcnt(4)" ::: "memory");
    } else {
      asm volatile("s_waitcnt vmcnt(0)" ::: "memory");
    }
    __builtin_amdgcn_sched_barrier(0);

    {
      u16* vt = Vt[cur];
#pragma unroll
      for (int j = 0; j < 8; ++j) {
        unsigned p0 = (unsigned)(unsigned short)vc[0][j] |
                      ((unsigned)(unsigned short)vc[1][j] << 16);
        *(unsigned*)&vt[(size_t)(d00 + j) * VST + kk20] = p0;
        unsigned p1 = (unsigned)(unsigned short)vc[2][j] |
                      ((unsigned)(unsigned short)vc[3][j] << 16);
        *(unsigned*)&vt[(size_t)(d01 + j) * VST + kk21] = p1;
      }
    }
    if (more) {
      const int kvn = kv0 + KB;
      vc[0] = *(const bf16x8*)(V + base + (size_t)(kvn + kk20) * D_ + d00);
      vc[1] = *(const bf16x8*)(V + base + (size_t)(kvn + kk20 + 1) * D_ + d00);
      vc[2] = *(const bf16x8*)(V + base + (size_t)(kvn + kk21) * D_ + d01);
      vc[3] = *(const bf16x8*)(V + base + (size_t)(kvn + kk21 + 1) * D_ + d01);
    }
    asm volatile("s_waitcnt lgkmcnt(0)" ::: "memory");
    __builtin_amdgcn_sched_barrier(0);
    __builtin_amdgcn_s_barrier();
    __builtin_amdgcn_sched_barrier(0);

    TILE_COMPUTE(qA, qrowA, qfA, mrowA, lrowA, oaccA);
    if (tt <= pr) {
      TILE_COMPUTE(qB, qrowB, qfB, mrowB, lrowB, oaccB);
    }

    __builtin_amdgcn_sched_barrier(0);
    __builtin_amdgcn_s_barrier();
    __builtin_amdgcn_sched_barrier(0);
  }

  {
    const float inv = 1.0f / lrowA;
    float ij[4];
#pragma unroll
    for (int j = 0; j < 4; ++j) ij[j] = __shfl(inv, lg * 4 + j, 64);
    u16* Op = O + base;
#pragma unroll
    for (int f = 0; f < 8; ++f)
#pragma unroll
      for (int j = 0; j < 4; ++j)
        Op[(size_t)(qA + w * 16 + lg * 4 + j) * D_ + f * 16 + lr] =
            f2bf(oaccA[f][j] * ij[j]);
  }
  {
    const float inv = 1.0f / lrowB;
    float ij[4];
#pragma unroll
    for (int j = 0; j < 4; ++j) ij[j] = __shfl(inv, lg * 4 + j, 64);
    u16* Op = O + base;
#pragma unroll
    for (int f = 0; f < 8; ++f)
#pragma unroll
      for (int j = 0; j < 4; ++j)
        Op[(size_t)(qB + w * 16 + lg * 4 + j) * D_ + f * 16 + lr] =
            f2bf(oaccB[f][j] * ij[j]);
  }
}
#undef TILE_COMPUTE

// grouped fallback
__global__ __launch_bounds__(256) void k_attn_g(const u16* __restrict__ Q,
                                                const u16* __restrict__ Kd,
                                                const u16* __restrict__ V,
                                                u16* __restrict__ O, int g) {
  const int by = blockIdx.y;
  const int b = by >> 2, hh = by & 3;
  const size_t base_in = ((size_t)b * S_) * GW + (size_t)hh * HD_;
  const size_t base_out = ((size_t)b * S_) * D_ + (size_t)(g * 4 + hh) * HD_;
  attn_body(Q, Kd, V, O, base_in, base_out, GW, D_, blockIdx.x * 64);
}

extern "C" void kernel_launch(void* const* d_in, const int* in_sizes, int n_in,
                              void* d_out, int out_size, void* d_ws,
                              size_t ws_size, hipStream_t stream) {
  (void)in_sizes; (void)n_in; (void)out_size;
  const float* x = (const float*)d_in[0];
  const float* wq = (const float*)d_in[1];
  const float* bq = (const float*)d_in[2];
  const float* wk = (const float*)d_in[3];
  const float* bk = (const float*)d_in[4];
  const float* wv = (const float*)d_in[5];
  const float* bv = (const float*)d_in[6];
  const float* wo = (const float*)d_in[7];
  const float* bo = (const float*)d_in[8];
  float* out = (float*)d_out;

  const size_t XB = (size_t)B_ * S_ * D_ * 2;  // 16,777,216
  const size_t WB3 = 3 * (size_t)D_ * D_ * 2;  // 25,165,824
  const size_t WB1 = (size_t)D_ * D_ * 2;      // 8,388,608
  const size_t TB = (size_t)S_ * 64 * 8;       // 1,048,576 rope table
  char* ws = (char*)d_ws;
  char* ob = (char*)d_out;

  u16 *xb, *q, *k, *v, *wqkvb = nullptr, *wob = nullptr;
  float2* tab = nullptr;
  int tier;
  if (ws_size >= 4 * XB + WB3 + WB1 + TB) {
    xb = (u16*)ws; q = (u16*)(ws + XB); k = (u16*)(ws + 2 * XB);
    v = (u16*)(ws + 3 * XB);
    wqkvb = (u16*)(ws + 4 * XB); wob = (u16*)(ws + 4 * XB + WB3);
    tab = (float2*)(ws + 4 * XB + WB3 + WB1);
    tier = 1;
  } else if (ws_size >= 3 * XB + WB3 + WB1 + TB) {
    xb = (u16*)ob;
    q = (u16*)ws; k = (u16*)(ws + XB); v = (u16*)(ws + 2 * XB);
    wqkvb = (u16*)(ws + 3 * XB); wob = (u16*)(ws + 3 * XB + WB3);
    tab = (float2*)(ws + 3 * XB + WB3 + WB1);
    tier = 1;
  } else if (ws_size >= 2 * XB + WB3 + TB) {
    xb = (u16*)ob; v = (u16*)(ob + XB);
    q = (u16*)ws; k = (u16*)(ws + XB);
    wqkvb = (u16*)(ws + 2 * XB);
    tab = (float2*)(ws + 2 * XB + WB3);
    tier = 2;
  } else if (ws_size >= 2 * XB) {
    xb = (u16*)ob; v = (u16*)(ob + XB);
    q = (u16*)ws; k = (u16*)(ws + XB);
    tier = 3;
  } else {
    tier = 4;
  }

  if (tier == 1 || tier == 2) {
    k_cvt_all<<<12800, 256, 0, stream>>>(x, wq, wk, wv, wo, xb, wqkvb, wob, tab);
    dim3 g1(16, 32, 3);
    k_gemm_qkv_bb<<<g1, 256, 0, stream>>>(xb, wqkvb, bq, bk, bv, q, k, v, tab);
    dim3 g2(16, 32);
    k_attn_full<<<g2, 256, 0, stream>>>(q, k, v, q);
    dim3 g3(16, 32);
    if (tier == 1)
      k_gemm_out_bb<<<g3, 256, 0, stream>>>(q, wob, bo, out);
    else
      k_gemm_out<<<g3, 256, 0, stream>>>(q, wo, bo, out);
  } else if (tier == 3) {
    k_cvt_all<<<4096, 256, 0, stream>>>(x, wq, wk, wv, wo, xb, xb, nullptr, nullptr);
    dim3 g1(16, 32, 3);
    k_gemm_qkv_xb<<<g1, 256, 0, stream>>>(xb, wq, bq, wk, bk, wv, bv, q, k, v);
    k_rope_full<<<16384, 256, 0, stream>>>(q, k);
    dim3 g2(16, 32);
    k_attn_full<<<g2, 256, 0, stream>>>(q, k, v, q);
    dim3 g3(16, 32);
    k_gemm_out<<<g3, 256, 0, stream>>>(q, wo, bo, out);
  } else {
    u16* qg = (u16*)ob;
    u16* kg = qg + (size_t)(B_ * S_) * GW;
    u16* vg = kg + (size_t)(B_ * S_) * GW;
    u16* ao = (u16*)ws;
    for (int g = 0; g < 4; ++g) {
      dim3 g1(4, 32, 3);
      k_gemm_qkv_g<<<g1, 256, 0, stream>>>(x, wq, bq, wk, bk, wv, bv, qg, kg, vg, g);
      k_rope_g<<<4096, 256, 0, stream>>>(qg, kg);
      dim3 g2(32, 8);
      k_attn_g<<<g2, 256, 0, stream>>>(qg, kg, vg, ao, g);
    }
    dim3 g3(16, 32);
    k_gemm_out<<<g3, 256, 0, stream>>>(ao, wo, bo, out);
  }
}